// Round 8
// baseline (186.659 us; speedup 1.0000x reference)
//
#include <hip/hip_runtime.h>
#include <hip/hip_bf16.h>

#define B_ 4
#define T_ 2048
#define D_ 512

typedef __attribute__((ext_vector_type(8))) short short8;
typedef __attribute__((ext_vector_type(4))) short short4v;
typedef __attribute__((ext_vector_type(4))) float float4v;
typedef unsigned short bf16_t;

__device__ __forceinline__ bf16_t f2bf(float f) {
  unsigned int u = __builtin_bit_cast(unsigned int, f);
  unsigned int r = (u + 0x7fffu + ((u >> 16) & 1u)) >> 16;
  return (bf16_t)r;
}
__device__ __forceinline__ float bf2f(bf16_t b) {
  unsigned int u = ((unsigned int)b) << 16;
  return __builtin_bit_cast(float, u);
}

// raw 2^x (v_exp_f32). Args always in-range here (or hugely negative -> 0).
__device__ __forceinline__ float fast_exp2(float x) {
#if __has_builtin(__builtin_amdgcn_exp2f)
  return __builtin_amdgcn_exp2f(x);
#else
  float r;
  asm("v_exp_f32 %0, %1" : "=v"(r) : "v"(x));
  return r;
#endif
}

// pack two f32 -> two bf16 (RNE) in one instruction: lo = src0, hi = src1
__device__ __forceinline__ unsigned cvt_pk_bf16(float lo, float hi) {
  unsigned r;
  asm("v_cvt_pk_bf16_f32 %0, %1, %2" : "=v"(r) : "v"(lo), "v"(hi));
  return r;
}

__device__ __forceinline__ float waveReduceSum(float v) {
#pragma unroll
  for (int m = 32; m >= 1; m >>= 1) v += __shfl_xor(v, m, 64);
  return v;
}

// async global->LDS 16B: LDS dest = wave-uniform base + lane*16
__device__ __forceinline__ void gld16(const bf16_t* g, bf16_t* l) {
  __builtin_amdgcn_global_load_lds(
      (const __attribute__((address_space(1))) void*)g,
      (__attribute__((address_space(3))) void*)l, 16, 0, 0);
}

// ---------------- fused: weight convert/transpose + LN1+PE ----------------
// Blocks [0,2048): LN1+PE rows. Blocks [2048,2304): LDS-tiled 64x64 weight
// transpose (coalesced f32 reads). wq scaled by log2(e), wk by 0.125.
__global__ __launch_bounds__(256) void pre_kernel(
    const float* __restrict__ x, const float* __restrict__ g,
    const float* __restrict__ bb,
    const float* __restrict__ wq, const float* __restrict__ wk,
    const float* __restrict__ wv, const float* __restrict__ wfc,
    bf16_t* __restrict__ h_bf16,
    bf16_t* __restrict__ wqkvT, bf16_t* __restrict__ wfcT) {
  if (blockIdx.x >= 2048) {
    __shared__ float tl[64][65];
    int bid = blockIdx.x - 2048;
    const float* src;
    float scl;
    int n0, k0;
    bf16_t* dst;
    if (bid < 192) {                        // wq|wk|wv -> wqkvT[n][k], n in [0,1536)
      n0 = (bid >> 3) * 64;
      k0 = (bid & 7) * 64;
      int m = n0 >> 9;
      src = (m == 0) ? wq : ((m == 1) ? wk : wv);
      scl = (m == 0) ? 1.4426950408889634f : ((m == 1) ? 0.125f : 1.0f);
      dst = wqkvT;
    } else {                                // wfc -> wfcT[n][k]
      int local = bid - 192;
      n0 = (local >> 3) * 64;
      k0 = (local & 7) * 64;
      src = wfc;
      scl = 1.0f;
      dst = wfcT;
    }
    int c0 = n0 & 511;
    int jl = threadIdx.x & 63, bi = threadIdx.x >> 6;
#pragma unroll
    for (int it = 0; it < 16; ++it) {
      int i = it * 4 + bi;                  // k-offset; reads are 256B-coalesced per wave
      tl[jl][i] = src[(size_t)(k0 + i) * 512 + c0 + jl] * scl;
    }
    __syncthreads();
    int i2 = (threadIdx.x & 31) * 2, jb = threadIdx.x >> 5;
#pragma unroll
    for (int it = 0; it < 8; ++it) {
      int j = it * 8 + jb;                  // n-offset
      unsigned pk = cvt_pk_bf16(tl[j][i2], tl[j][i2 + 1]);
      *(unsigned*)(dst + (size_t)(n0 + j) * 512 + k0 + i2) = pk;
    }
    return;
  }
  int wave = threadIdx.x >> 6, lane = threadIdx.x & 63;
  int row = blockIdx.x * 4 + wave;
  int pos = row & (T_ - 1);
  const float* xr = x + (size_t)row * D_;
  int c0 = lane * 8;
  float v[8];
  float4 a = *(const float4*)(xr + c0);
  float4 b4 = *(const float4*)(xr + c0 + 4);
  v[0]=a.x; v[1]=a.y; v[2]=a.z; v[3]=a.w;
  v[4]=b4.x; v[5]=b4.y; v[6]=b4.z; v[7]=b4.w;
  float s = 0.f;
#pragma unroll
  for (int j = 0; j < 8; ++j) s += v[j];
  s = waveReduceSum(s);
  float mu = s * (1.f / 512.f);
  float q = 0.f;
#pragma unroll
  for (int j = 0; j < 8; ++j) { float d = v[j] - mu; q += d * d; }
  q = waveReduceSum(q);
  float rstd = rsqrtf(q * (1.f / 512.f) + 1e-5f);
  bf16_t* hb = h_bf16 + (size_t)row * D_;
  float fpos = (float)pos;
#pragma unroll
  for (int jp = 0; jp < 4; ++jp) {
    int col = c0 + jp * 2;
    float dt = fast_exp2((float)col * (-13.287712379549449f / 512.0f));
    float ang = fpos * dt;
    float hn0 = (v[2 * jp] - mu) * rstd * g[col] + bb[col] + __sinf(ang);
    float hn1 = (v[2 * jp + 1] - mu) * rstd * g[col + 1] + bb[col + 1] + __cosf(ang);
    hb[col] = f2bf(hn0);
    hb[col + 1] = f2bf(hn1);
  }
}

// ---------------- 128x128 GEMM, single-buffer m97 structure (32 KB LDS) ----------------
template <typename EPI>
__device__ __forceinline__ void gemm_body(const bf16_t* __restrict__ A,
                                          const bf16_t* __restrict__ Bt,
                                          int m0, int n0, bf16_t* As, bf16_t* Bs,
                                          EPI epi) {
  const int tid = threadIdx.x;
  const int w = tid >> 6, lane = tid & 63;
  const int ln = lane & 15, quad = lane >> 4;
  const int wy = w >> 1, wx = w & 1;
  const int sw = ln & 7;

  float4v acc[4][4];
  float4v z = {0.f, 0.f, 0.f, 0.f};
#pragma unroll
  for (int i = 0; i < 4; ++i)
#pragma unroll
    for (int j = 0; j < 4; ++j) acc[i][j] = z;

  for (int k0 = 0; k0 < 512; k0 += 64) {
#pragma unroll
    for (int i = 0; i < 4; ++i) {
      int cbase = w * 256 + i * 64;
      int chunk = cbase + lane;
      int row = chunk >> 3;
      int lb = (chunk & 7) ^ (row & 7);
      gld16(A + (size_t)(m0 + row) * 512 + k0 + lb * 8, As + cbase * 8);
      gld16(Bt + (size_t)(n0 + row) * 512 + k0 + lb * 8, Bs + cbase * 8);
    }
    __syncthreads();
#pragma unroll
    for (int c = 0; c < 2; ++c) {
      short8 af[4], bf[4];
#pragma unroll
      for (int mt = 0; mt < 4; ++mt)
        af[mt] = *(const short8*)(As + (wy * 64 + mt * 16 + ln) * 64 + (((c * 4 + quad) ^ sw)) * 8);
#pragma unroll
      for (int nt = 0; nt < 4; ++nt)
        bf[nt] = *(const short8*)(Bs + (wx * 64 + nt * 16 + ln) * 64 + (((c * 4 + quad) ^ sw)) * 8);
#pragma unroll
      for (int mt = 0; mt < 4; ++mt)
#pragma unroll
        for (int nt = 0; nt < 4; ++nt)
          acc[mt][nt] = __builtin_amdgcn_mfma_f32_16x16x32_bf16(af[mt], bf[nt], acc[mt][nt], 0, 0, 0);
    }
    __syncthreads();
  }
#pragma unroll
  for (int mt = 0; mt < 4; ++mt)
#pragma unroll
    for (int r = 0; r < 4; ++r) {
      int row = m0 + wy * 64 + mt * 16 + quad * 4 + r;
#pragma unroll
      for (int nt = 0; nt < 4; ++nt) {
        int col = n0 + wx * 64 + nt * 16 + ln;
        epi(row, col, acc[mt][nt][r]);
      }
    }
}

// ---------------- 64x128 GEMM body (24 KB LDS) — for the small out-proj ----------------
template <typename EPI>
__device__ __forceinline__ void gemm_body_64x128(const bf16_t* __restrict__ A,
                                                 const bf16_t* __restrict__ Bt,
                                                 int m0, int n0, bf16_t* As, bf16_t* Bs,
                                                 EPI epi) {
  const int tid = threadIdx.x;
  const int w = tid >> 6, lane = tid & 63;
  const int ln = lane & 15, quad = lane >> 4;
  const int wy = w >> 1, wx = w & 1;
  const int sw = ln & 7;

  float4v acc[2][4];
  float4v z = {0.f, 0.f, 0.f, 0.f};
#pragma unroll
  for (int i = 0; i < 2; ++i)
#pragma unroll
    for (int j = 0; j < 4; ++j) acc[i][j] = z;

  for (int k0 = 0; k0 < 512; k0 += 64) {
#pragma unroll
    for (int i = 0; i < 2; ++i) {           // A: 64 rows -> 512 chunks
      int cbase = i * 256 + w * 64;
      int chunk = cbase + lane;
      int row = chunk >> 3;
      int lb = (chunk & 7) ^ (row & 7);
      gld16(A + (size_t)(m0 + row) * 512 + k0 + lb * 8, As + cbase * 8);
    }
#pragma unroll
    for (int i = 0; i < 4; ++i) {           // B: 128 rows -> 1024 chunks
      int cbase = i * 256 + w * 64;
      int chunk = cbase + lane;
      int row = chunk >> 3;
      int lb = (chunk & 7) ^ (row & 7);
      gld16(Bt + (size_t)(n0 + row) * 512 + k0 + lb * 8, Bs + cbase * 8);
    }
    __syncthreads();
#pragma unroll
    for (int c = 0; c < 2; ++c) {
      short8 af[2], bf[4];
#pragma unroll
      for (int mt = 0; mt < 2; ++mt)
        af[mt] = *(const short8*)(As + (wy * 32 + mt * 16 + ln) * 64 + (((c * 4 + quad) ^ sw)) * 8);
#pragma unroll
      for (int nt = 0; nt < 4; ++nt)
        bf[nt] = *(const short8*)(Bs + (wx * 64 + nt * 16 + ln) * 64 + (((c * 4 + quad) ^ sw)) * 8);
#pragma unroll
      for (int mt = 0; mt < 2; ++mt)
#pragma unroll
        for (int nt = 0; nt < 4; ++nt)
          acc[mt][nt] = __builtin_amdgcn_mfma_f32_16x16x32_bf16(af[mt], bf[nt], acc[mt][nt], 0, 0, 0);
    }
    __syncthreads();
  }
#pragma unroll
  for (int mt = 0; mt < 2; ++mt)
#pragma unroll
    for (int r = 0; r < 4; ++r) {
      int row = m0 + wy * 32 + mt * 16 + quad * 4 + r;
#pragma unroll
      for (int nt = 0; nt < 4; ++nt) {
        int col = n0 + wx * 64 + nt * 16 + ln;
        epi(row, col, acc[mt][nt][r]);
      }
    }
}

// blocks [0,512): QK proj -> qk[8192][1024]; [512,768): V^T -> vT[512][8192]
__global__ __launch_bounds__(256) void gemm_qkvt_kernel(
    const bf16_t* __restrict__ h_bf, const bf16_t* __restrict__ wqkvT,
    bf16_t* __restrict__ qk, bf16_t* __restrict__ vT) {
  __shared__ __align__(16) bf16_t As[128 * 64];
  __shared__ __align__(16) bf16_t Bs[128 * 64];
  int bx = blockIdx.x;
  if (bx < 512) {
    int m0 = (bx >> 3) * 128, n0 = (bx & 7) * 128;
    gemm_body(h_bf, wqkvT, m0, n0, As, Bs,
              [&](int row, int col, float v) { qk[(size_t)row * 1024 + col] = f2bf(v); });
  } else {
    int local = bx - 512;
    int m0 = (local >> 6) * 128, n0 = (local & 63) * 128;
    gemm_body(wqkvT + 1024 * 512, h_bf, m0, n0, As, Bs,
              [&](int row, int col, float v) { vT[(size_t)row * 8192 + col] = f2bf(v); });
  }
}

// out-proj GEMM + residual (h_bf) epilogue -> o2r bf16 [8192][512]; 512 blocks (2/CU)
__global__ __launch_bounds__(256) void gemm_out_kernel(
    const bf16_t* __restrict__ attn, const bf16_t* __restrict__ wfcT,
    const bf16_t* __restrict__ h_bf, bf16_t* __restrict__ o2r) {
  __shared__ __align__(16) bf16_t As[64 * 64];
  __shared__ __align__(16) bf16_t Bs[128 * 64];
  int bx = blockIdx.x;
  int m0 = (bx >> 2) * 64, n0 = (bx & 3) * 128;
  gemm_body_64x128(attn, wfcT, m0, n0, As, Bs, [&](int row, int col, float v) {
    size_t o = (size_t)row * 512 + col;
    o2r[o] = f2bf(v + bf2f(h_bf[o]));
  });
}

// ---------------- flash-style causal attention, 128-q blocks, single pass ----------------
// qk: [B*T][1024] bf16 (Q*log2e | K*0.125 pre-scaled), vT: [512][8192] bf16.
// 512 blocks (t desc, b, h), plain order (NO XCD affinity — R5 showed it causes
// 3x write amplification). Each block covers 128 q-rows as two 64-row sets that
// SHARE every K/V LDS tile and every K/V fragment ds_read — per-q-row issue work
// (the measured limiter across R1/R2/R4 schedules) drops ~25%, K/V L2 traffic
// halves. Compute/mask logic is R5's correctness-proven version; output is
// normalized in-kernel (no split-K, no combine).
// Per k-tile j: set0 (rows t*128..+63) active iff j<=2t, masked at j==2t;
//              set1 (rows t*128+64..+127) masked at j==2t+1.
__global__ __launch_bounds__(256) void attn_kernel(const bf16_t* __restrict__ qk,
                                                   const bf16_t* __restrict__ vT,
                                                   bf16_t* __restrict__ out) {
  __shared__ __align__(16) bf16_t Ks[2][64 * 64];
  __shared__ __align__(16) bf16_t Vs[2][64 * 64];
  const int bx = blockIdx.x;
  const int t = 15 - (bx >> 5);       // 128-row q-tile, long-first
  const int bh = bx & 31;
  const int b = bh >> 3, h = bh & 7;
  const int tid = threadIdx.x;
  const int w = tid >> 6, lane = tid & 63;
  const int ln = lane & 15, quad = lane >> 4;
  const int sw = ln & 7;

  const int Nt = 2 * t + 2;           // k-tiles covering keys 0..t*128+127

  short8 qf[2][2];
#pragma unroll
  for (int s = 0; s < 2; ++s) {
    size_t qrow = ((size_t)b * T_ + t * 128 + s * 64 + w * 16 + ln) * 1024 + h * 64;
    qf[s][0] = *(const short8*)(qk + qrow + quad * 8);
    qf[s][1] = *(const short8*)(qk + qrow + 32 + quad * 8);
  }
  float4v z = {0.f, 0.f, 0.f, 0.f};
  float4v oacc[2][4];
#pragma unroll
  for (int s = 0; s < 2; ++s)
#pragma unroll
    for (int i = 0; i < 4; ++i) oacc[s][i] = z;
  float m_s[2] = {-1e30f, -1e30f}, l_s[2] = {0.f, 0.f};

  const bf16_t* kbase = qk + (size_t)b * T_ * 1024 + 512 + h * 64;
  const bf16_t* vbase = vT + (size_t)(h * 64) * 8192 + (size_t)b * T_;

  // hoisted per-lane staging addresses; advanced by constant strides per tile
  const int cb0 = w * 128, cb1 = w * 128 + 64;
  const int ch0 = cb0 + lane, ch1 = cb1 + lane;
  const int r0 = ch0 >> 3, r1 = ch1 >> 3;
  const int lb0 = (ch0 & 7) ^ (r0 & 7), lb1 = (ch1 & 7) ^ (r1 & 7);
  const bf16_t* kg0 = kbase + (size_t)r0 * 1024 + lb0 * 8;
  const bf16_t* kg1 = kbase + (size_t)r1 * 1024 + lb1 * 8;
  const bf16_t* vg0 = vbase + (size_t)r0 * 8192 + lb0 * 8;
  const bf16_t* vg1 = vbase + (size_t)r1 * 8192 + lb1 * 8;

  auto stage2 = [&](int buf) {
    gld16(kg0, Ks[buf] + cb0 * 8);
    gld16(kg1, Ks[buf] + cb1 * 8);
    gld16(vg0, Vs[buf] + cb0 * 8);
    gld16(vg1, Vs[buf] + cb1 * 8);
    kg0 += 64 * 1024; kg1 += 64 * 1024;   // next K tile (64 rows)
    vg0 += 64;        vg1 += 64;          // next V^T tile (64 cols)
  };

  // one softmax step for one q-set: sv (exp'd in place), updates m/l, emits pf
  auto softmax = [&](float sv[4][4], float& ms, float& ls, float4v* oa, short4v* pf) {
    float mxa[4];
#pragma unroll
    for (int mt = 0; mt < 4; ++mt)
      mxa[mt] = fmaxf(fmaxf(sv[mt][0], sv[mt][1]), fmaxf(sv[mt][2], sv[mt][3]));
    float mx = fmaxf(fmaxf(mxa[0], mxa[1]), fmaxf(mxa[2], mxa[3]));
    mx = fmaxf(mx, __shfl_xor(mx, 16, 64));
    mx = fmaxf(mx, __shfl_xor(mx, 32, 64));
    if (!__all(mx <= ms + 8.0f)) {        // defer-max, THR=8 (2^8 headroom)
      float mn = fmaxf(ms, mx);
      float alpha = fast_exp2(ms - mn);
      ms = mn;
      ls *= alpha;
#pragma unroll
      for (int dt = 0; dt < 4; ++dt)
#pragma unroll
        for (int r = 0; r < 4; ++r) oa[dt][r] *= alpha;
    }
    float rsa[4];
#pragma unroll
    for (int mt = 0; mt < 4; ++mt) {
#pragma unroll
      for (int r = 0; r < 4; ++r) sv[mt][r] = fast_exp2(sv[mt][r] - ms);
      rsa[mt] = (sv[mt][0] + sv[mt][1]) + (sv[mt][2] + sv[mt][3]);
    }
    float rs = (rsa[0] + rsa[1]) + (rsa[2] + rsa[3]);
    rs += __shfl_xor(rs, 16, 64);
    rs += __shfl_xor(rs, 32, 64);
    ls += rs;
#pragma unroll
    for (int mt = 0; mt < 4; ++mt) {
      uint2 pp;
      pp.x = cvt_pk_bf16(sv[mt][0], sv[mt][1]);
      pp.y = cvt_pk_bf16(sv[mt][2], sv[mt][3]);
      pf[mt] = __builtin_bit_cast(short4v, pp);
    }
  };

  auto compute = [&](const bf16_t* Kc, const bf16_t* Vc,
                     bool act0, bool mask0, bool mask1) {
    float sv0[4][4], sv1[4][4];
#pragma unroll
    for (int mt = 0; mt < 4; ++mt) {
      int row = mt * 16 + ln;
      short8 a0 = *(const short8*)(Kc + row * 64 + ((0 + quad) ^ sw) * 8);
      short8 a1 = *(const short8*)(Kc + row * 64 + ((4 + quad) ^ sw) * 8);
      float4v st1 = z;
      st1 = __builtin_amdgcn_mfma_f32_16x16x32_bf16(a0, qf[1][0], st1, 0, 0, 0);
      st1 = __builtin_amdgcn_mfma_f32_16x16x32_bf16(a1, qf[1][1], st1, 0, 0, 0);
      if (act0) {
        float4v st0 = z;
        st0 = __builtin_amdgcn_mfma_f32_16x16x32_bf16(a0, qf[0][0], st0, 0, 0, 0);
        st0 = __builtin_amdgcn_mfma_f32_16x16x32_bf16(a1, qf[0][1], st0, 0, 0, 0);
#pragma unroll
        for (int r = 0; r < 4; ++r) {
          float v = st0[r];
          if (mask0) {
            int kloc = mt * 16 + quad * 4 + r;
            if (kloc > w * 16 + ln) v = -1e30f;
          }
          sv0[mt][r] = v;
        }
      }
#pragma unroll
      for (int r = 0; r < 4; ++r) {
        float v = st1[r];
        if (mask1) {
          int kloc = mt * 16 + quad * 4 + r;
          if (kloc > w * 16 + ln) v = -1e30f;
        }
        sv1[mt][r] = v;
      }
    }
    short4v pf0[4], pf1[4];
    if (act0) softmax(sv0, m_s[0], l_s[0], oacc[0], pf0);
    softmax(sv1, m_s[1], l_s[1], oacc[1], pf1);
    // O^T += V^T P : A = V^T frags (shared by both q-sets), B = pf
#pragma unroll
    for (int dt = 0; dt < 4; ++dt) {
      int row = dt * 16 + ln;
#pragma unroll
      for (int mt = 0; mt < 4; ++mt) {
        short4v av = *(const short4v*)(Vc + row * 64 + ((2 * mt + (quad >> 1)) ^ sw) * 8 + (quad & 1) * 4);
        if (act0)
          oacc[0][dt] = __builtin_amdgcn_mfma_f32_16x16x16bf16_1k(av, pf0[mt], oacc[0][dt], 0, 0, 0);
        oacc[1][dt] = __builtin_amdgcn_mfma_f32_16x16x16bf16_1k(av, pf1[mt], oacc[1][dt], 0, 0, 0);
      }
    }
  };

  stage2(0);
  __syncthreads();
  for (int i = 0; i < Nt; ++i) {
    int cur = i & 1;
    if (i + 1 < Nt) stage2(cur ^ 1);
    compute(Ks[cur], Vs[cur], i <= 2 * t, i == 2 * t, i == 2 * t + 1);
    if (i + 1 < Nt) __syncthreads();
  }

#pragma unroll
  for (int s = 0; s < 2; ++s) {
    float inv = 1.0f / l_s[s];
    size_t obase = ((size_t)b * T_ + t * 128 + s * 64 + w * 16 + ln) * 512 + h * 64;
#pragma unroll
    for (int dt = 0; dt < 4; ++dt) {
      short4v o4;
#pragma unroll
      for (int r = 0; r < 4; ++r) o4[r] = (short)f2bf(oacc[s][dt][r] * inv);
      *(short4v*)(out + obase + dt * 16 + quad * 4) = o4;
    }
  }
}

// ---------------- final LN + residual ----------------
__global__ __launch_bounds__(256) void ln2_kernel(
    const bf16_t* __restrict__ o2r, const float* __restrict__ x,
    const float* __restrict__ g, const float* __restrict__ bb,
    float* __restrict__ out) {
  int wave = threadIdx.x >> 6, lane = threadIdx.x & 63;
  int row = blockIdx.x * 4 + wave;
  size_t ro = (size_t)row * D_;
  int c0 = lane * 8;
  short8 ov = *(const short8*)(o2r + ro + c0);
  float t[8];
#pragma unroll
  for (int j = 0; j < 8; ++j) t[j] = bf2f((bf16_t)ov[j]);
  float s = 0.f;
#pragma unroll
  for (int j = 0; j < 8; ++j) s += t[j];
  s = waveReduceSum(s);
  float mu = s * (1.f / 512.f);
  float q = 0.f;
#pragma unroll
  for (int j = 0; j < 8; ++j) { float d = t[j] - mu; q += d * d; }
  q = waveReduceSum(q);
  float rstd = rsqrtf(q * (1.f / 512.f) + 1e-6f);
  float4 x0 = *(const float4*)(x + ro + c0);
  float4 x1 = *(const float4*)(x + ro + c0 + 4);
  float xr[8] = {x0.x, x0.y, x0.z, x0.w, x1.x, x1.y, x1.z, x1.w};
  float o[8];
#pragma unroll
  for (int j = 0; j < 8; ++j) {
    int col = c0 + j;
    o[j] = (t[j] - mu) * rstd * g[col] + bb[col] + xr[j];
  }
  float4 w0 = {o[0], o[1], o[2], o[3]};
  float4 w1 = {o[4], o[5], o[6], o[7]};
  *(float4*)(out + ro + c0) = w0;
  *(float4*)(out + ro + c0 + 4) = w1;
}

// ---------------- launch ----------------
extern "C" void kernel_launch(void* const* d_in, const int* in_sizes, int n_in,
                              void* d_out, int out_size, void* d_ws, size_t ws_size,
                              hipStream_t stream) {
  const float* x   = (const float*)d_in[0];
  const float* g1  = (const float*)d_in[1];
  const float* b1  = (const float*)d_in[2];
  const float* wq  = (const float*)d_in[3];
  const float* wk  = (const float*)d_in[4];
  const float* wv  = (const float*)d_in[5];
  const float* wfc = (const float*)d_in[6];
  const float* g2  = (const float*)d_in[7];
  const float* b2  = (const float*)d_in[8];
  float* out = (float*)d_out;

  char* ws = (char*)d_ws;
  const size_t O_HBF  = 0;          // 8192*512*2  =  8388608
  const size_t O_WQKV = 8388608;    // 1536*512*2  =  1572864
  const size_t O_WFC  = 9961472;    //  512*512*2  =   524288
  const size_t O_QK   = 10485760;   // 8192*1024*2 = 16777216
  const size_t O_VT   = 27262976;   //  512*8192*2 =  8388608
  const size_t O_ATTN = 35651584;   // 8192*512*2  =  8388608
  const size_t O_O2R  = 44040192;   // 8192*512*2  =  8388608
  const size_t WS_NEED = 52428800;
  if (ws_size < WS_NEED) return;

  bf16_t* h_bf  = (bf16_t*)(ws + O_HBF);
  bf16_t* wqkvT = (bf16_t*)(ws + O_WQKV);
  bf16_t* wfcT  = (bf16_t*)(ws + O_WFC);
  bf16_t* qk    = (bf16_t*)(ws + O_QK);
  bf16_t* vT    = (bf16_t*)(ws + O_VT);
  bf16_t* attn  = (bf16_t*)(ws + O_ATTN);
  bf16_t* o2r   = (bf16_t*)(ws + O_O2R);

  pre_kernel<<<dim3(2304), dim3(256), 0, stream>>>(x, g1, b1, wq, wk, wv, wfc,
                                                   h_bf, wqkvT, wfcT);
  gemm_qkvt_kernel<<<dim3(768), dim3(256), 0, stream>>>(h_bf, wqkvT, qk, vT);
  attn_kernel<<<dim3(512), dim3(256), 0, stream>>>(qk, vT, attn);
  gemm_out_kernel<<<dim3(512), dim3(256), 0, stream>>>(attn, wfcT, h_bf, o2r);
  ln2_kernel<<<dim3(2048), dim3(256), 0, stream>>>(o2r, x, g2, b2, out);
}

// Round 9
// 165.178 us; speedup vs baseline: 1.1300x; 1.1300x over previous
//
#include <hip/hip_runtime.h>
#include <hip/hip_bf16.h>

#define B_ 4
#define T_ 2048
#define D_ 512

typedef __attribute__((ext_vector_type(8))) short short8;
typedef __attribute__((ext_vector_type(4))) short short4v;
typedef __attribute__((ext_vector_type(4))) float float4v;
typedef unsigned short bf16_t;

__device__ __forceinline__ bf16_t f2bf(float f) {
  unsigned int u = __builtin_bit_cast(unsigned int, f);
  unsigned int r = (u + 0x7fffu + ((u >> 16) & 1u)) >> 16;
  return (bf16_t)r;
}
__device__ __forceinline__ float bf2f(bf16_t b) {
  unsigned int u = ((unsigned int)b) << 16;
  return __builtin_bit_cast(float, u);
}

// raw 2^x (v_exp_f32). Args always in-range here (or hugely negative -> 0).
__device__ __forceinline__ float fast_exp2(float x) {
#if __has_builtin(__builtin_amdgcn_exp2f)
  return __builtin_amdgcn_exp2f(x);
#else
  float r;
  asm("v_exp_f32 %0, %1" : "=v"(r) : "v"(x));
  return r;
#endif
}

// pack two f32 -> two bf16 (RNE) in one instruction: lo = src0, hi = src1
__device__ __forceinline__ unsigned cvt_pk_bf16(float lo, float hi) {
  unsigned r;
  asm("v_cvt_pk_bf16_f32 %0, %1, %2" : "=v"(r) : "v"(lo), "v"(hi));
  return r;
}

__device__ __forceinline__ float waveReduceSum(float v) {
#pragma unroll
  for (int m = 32; m >= 1; m >>= 1) v += __shfl_xor(v, m, 64);
  return v;
}

// async global->LDS 16B: LDS dest = wave-uniform base + lane*16
__device__ __forceinline__ void gld16(const bf16_t* g, bf16_t* l) {
  __builtin_amdgcn_global_load_lds(
      (const __attribute__((address_space(1))) void*)g,
      (__attribute__((address_space(3))) void*)l, 16, 0, 0);
}

// ---------------- fused: weight convert/transpose + LN1+PE ----------------
// Blocks [0,2048): LN1+PE rows. Blocks [2048,2304): LDS-tiled 64x64 weight
// transpose (coalesced f32 reads). wq scaled by log2(e), wk by 0.125.
__global__ __launch_bounds__(256) void pre_kernel(
    const float* __restrict__ x, const float* __restrict__ g,
    const float* __restrict__ bb,
    const float* __restrict__ wq, const float* __restrict__ wk,
    const float* __restrict__ wv, const float* __restrict__ wfc,
    bf16_t* __restrict__ h_bf16,
    bf16_t* __restrict__ wqkvT, bf16_t* __restrict__ wfcT) {
  if (blockIdx.x >= 2048) {
    __shared__ float tl[64][65];
    int bid = blockIdx.x - 2048;
    const float* src;
    float scl;
    int n0, k0;
    bf16_t* dst;
    if (bid < 192) {                        // wq|wk|wv -> wqkvT[n][k], n in [0,1536)
      n0 = (bid >> 3) * 64;
      k0 = (bid & 7) * 64;
      int m = n0 >> 9;
      src = (m == 0) ? wq : ((m == 1) ? wk : wv);
      scl = (m == 0) ? 1.4426950408889634f : ((m == 1) ? 0.125f : 1.0f);
      dst = wqkvT;
    } else {                                // wfc -> wfcT[n][k]
      int local = bid - 192;
      n0 = (local >> 3) * 64;
      k0 = (local & 7) * 64;
      src = wfc;
      scl = 1.0f;
      dst = wfcT;
    }
    int c0 = n0 & 511;
    int jl = threadIdx.x & 63, bi = threadIdx.x >> 6;
#pragma unroll
    for (int it = 0; it < 16; ++it) {
      int i = it * 4 + bi;                  // k-offset; reads are 256B-coalesced per wave
      tl[jl][i] = src[(size_t)(k0 + i) * 512 + c0 + jl] * scl;
    }
    __syncthreads();
    int i2 = (threadIdx.x & 31) * 2, jb = threadIdx.x >> 5;
#pragma unroll
    for (int it = 0; it < 8; ++it) {
      int j = it * 8 + jb;                  // n-offset
      unsigned pk = cvt_pk_bf16(tl[j][i2], tl[j][i2 + 1]);
      *(unsigned*)(dst + (size_t)(n0 + j) * 512 + k0 + i2) = pk;
    }
    return;
  }
  int wave = threadIdx.x >> 6, lane = threadIdx.x & 63;
  int row = blockIdx.x * 4 + wave;
  int pos = row & (T_ - 1);
  const float* xr = x + (size_t)row * D_;
  int c0 = lane * 8;
  float v[8];
  float4 a = *(const float4*)(xr + c0);
  float4 b4 = *(const float4*)(xr + c0 + 4);
  v[0]=a.x; v[1]=a.y; v[2]=a.z; v[3]=a.w;
  v[4]=b4.x; v[5]=b4.y; v[6]=b4.z; v[7]=b4.w;
  float s = 0.f;
#pragma unroll
  for (int j = 0; j < 8; ++j) s += v[j];
  s = waveReduceSum(s);
  float mu = s * (1.f / 512.f);
  float q = 0.f;
#pragma unroll
  for (int j = 0; j < 8; ++j) { float d = v[j] - mu; q += d * d; }
  q = waveReduceSum(q);
  float rstd = rsqrtf(q * (1.f / 512.f) + 1e-5f);
  bf16_t* hb = h_bf16 + (size_t)row * D_;
  float fpos = (float)pos;
#pragma unroll
  for (int jp = 0; jp < 4; ++jp) {
    int col = c0 + jp * 2;
    float dt = fast_exp2((float)col * (-13.287712379549449f / 512.0f));
    float ang = fpos * dt;
    float hn0 = (v[2 * jp] - mu) * rstd * g[col] + bb[col] + __sinf(ang);
    float hn1 = (v[2 * jp + 1] - mu) * rstd * g[col + 1] + bb[col + 1] + __cosf(ang);
    hb[col] = f2bf(hn0);
    hb[col + 1] = f2bf(hn1);
  }
}

// ---------------- 128x128 GEMM, single-buffer m97 structure (32 KB LDS) ----------------
template <typename EPI>
__device__ __forceinline__ void gemm_body(const bf16_t* __restrict__ A,
                                          const bf16_t* __restrict__ Bt,
                                          int m0, int n0, bf16_t* As, bf16_t* Bs,
                                          EPI epi) {
  const int tid = threadIdx.x;
  const int w = tid >> 6, lane = tid & 63;
  const int ln = lane & 15, quad = lane >> 4;
  const int wy = w >> 1, wx = w & 1;
  const int sw = ln & 7;

  float4v acc[4][4];
  float4v z = {0.f, 0.f, 0.f, 0.f};
#pragma unroll
  for (int i = 0; i < 4; ++i)
#pragma unroll
    for (int j = 0; j < 4; ++j) acc[i][j] = z;

  for (int k0 = 0; k0 < 512; k0 += 64) {
#pragma unroll
    for (int i = 0; i < 4; ++i) {
      int cbase = w * 256 + i * 64;
      int chunk = cbase + lane;
      int row = chunk >> 3;
      int lb = (chunk & 7) ^ (row & 7);
      gld16(A + (size_t)(m0 + row) * 512 + k0 + lb * 8, As + cbase * 8);
      gld16(Bt + (size_t)(n0 + row) * 512 + k0 + lb * 8, Bs + cbase * 8);
    }
    __syncthreads();
#pragma unroll
    for (int c = 0; c < 2; ++c) {
      short8 af[4], bf[4];
#pragma unroll
      for (int mt = 0; mt < 4; ++mt)
        af[mt] = *(const short8*)(As + (wy * 64 + mt * 16 + ln) * 64 + (((c * 4 + quad) ^ sw)) * 8);
#pragma unroll
      for (int nt = 0; nt < 4; ++nt)
        bf[nt] = *(const short8*)(Bs + (wx * 64 + nt * 16 + ln) * 64 + (((c * 4 + quad) ^ sw)) * 8);
#pragma unroll
      for (int mt = 0; mt < 4; ++mt)
#pragma unroll
        for (int nt = 0; nt < 4; ++nt)
          acc[mt][nt] = __builtin_amdgcn_mfma_f32_16x16x32_bf16(af[mt], bf[nt], acc[mt][nt], 0, 0, 0);
    }
    __syncthreads();
  }
#pragma unroll
  for (int mt = 0; mt < 4; ++mt)
#pragma unroll
    for (int r = 0; r < 4; ++r) {
      int row = m0 + wy * 64 + mt * 16 + quad * 4 + r;
#pragma unroll
      for (int nt = 0; nt < 4; ++nt) {
        int col = n0 + wx * 64 + nt * 16 + ln;
        epi(row, col, acc[mt][nt][r]);
      }
    }
}

// ---------------- 64x128 GEMM body (24 KB LDS) — for the small out-proj ----------------
template <typename EPI>
__device__ __forceinline__ void gemm_body_64x128(const bf16_t* __restrict__ A,
                                                 const bf16_t* __restrict__ Bt,
                                                 int m0, int n0, bf16_t* As, bf16_t* Bs,
                                                 EPI epi) {
  const int tid = threadIdx.x;
  const int w = tid >> 6, lane = tid & 63;
  const int ln = lane & 15, quad = lane >> 4;
  const int wy = w >> 1, wx = w & 1;
  const int sw = ln & 7;

  float4v acc[2][4];
  float4v z = {0.f, 0.f, 0.f, 0.f};
#pragma unroll
  for (int i = 0; i < 2; ++i)
#pragma unroll
    for (int j = 0; j < 4; ++j) acc[i][j] = z;

  for (int k0 = 0; k0 < 512; k0 += 64) {
#pragma unroll
    for (int i = 0; i < 2; ++i) {           // A: 64 rows -> 512 chunks
      int cbase = i * 256 + w * 64;
      int chunk = cbase + lane;
      int row = chunk >> 3;
      int lb = (chunk & 7) ^ (row & 7);
      gld16(A + (size_t)(m0 + row) * 512 + k0 + lb * 8, As + cbase * 8);
    }
#pragma unroll
    for (int i = 0; i < 4; ++i) {           // B: 128 rows -> 1024 chunks
      int cbase = i * 256 + w * 64;
      int chunk = cbase + lane;
      int row = chunk >> 3;
      int lb = (chunk & 7) ^ (row & 7);
      gld16(Bt + (size_t)(n0 + row) * 512 + k0 + lb * 8, Bs + cbase * 8);
    }
    __syncthreads();
#pragma unroll
    for (int c = 0; c < 2; ++c) {
      short8 af[2], bf[4];
#pragma unroll
      for (int mt = 0; mt < 2; ++mt)
        af[mt] = *(const short8*)(As + (wy * 32 + mt * 16 + ln) * 64 + (((c * 4 + quad) ^ sw)) * 8);
#pragma unroll
      for (int nt = 0; nt < 4; ++nt)
        bf[nt] = *(const short8*)(Bs + (wx * 64 + nt * 16 + ln) * 64 + (((c * 4 + quad) ^ sw)) * 8);
#pragma unroll
      for (int mt = 0; mt < 2; ++mt)
#pragma unroll
        for (int nt = 0; nt < 4; ++nt)
          acc[mt][nt] = __builtin_amdgcn_mfma_f32_16x16x32_bf16(af[mt], bf[nt], acc[mt][nt], 0, 0, 0);
    }
    __syncthreads();
  }
#pragma unroll
  for (int mt = 0; mt < 2; ++mt)
#pragma unroll
    for (int r = 0; r < 4; ++r) {
      int row = m0 + wy * 32 + mt * 16 + quad * 4 + r;
#pragma unroll
      for (int nt = 0; nt < 4; ++nt) {
        int col = n0 + wx * 64 + nt * 16 + ln;
        epi(row, col, acc[mt][nt][r]);
      }
    }
}

// blocks [0,512): QK proj -> qk[8192][1024]; [512,768): V^T -> vT[512][8192]
__global__ __launch_bounds__(256) void gemm_qkvt_kernel(
    const bf16_t* __restrict__ h_bf, const bf16_t* __restrict__ wqkvT,
    bf16_t* __restrict__ qk, bf16_t* __restrict__ vT) {
  __shared__ __align__(16) bf16_t As[128 * 64];
  __shared__ __align__(16) bf16_t Bs[128 * 64];
  int bx = blockIdx.x;
  if (bx < 512) {
    int m0 = (bx >> 3) * 128, n0 = (bx & 7) * 128;
    gemm_body(h_bf, wqkvT, m0, n0, As, Bs,
              [&](int row, int col, float v) { qk[(size_t)row * 1024 + col] = f2bf(v); });
  } else {
    int local = bx - 512;
    int m0 = (local >> 6) * 128, n0 = (local & 63) * 128;
    gemm_body(wqkvT + 1024 * 512, h_bf, m0, n0, As, Bs,
              [&](int row, int col, float v) { vT[(size_t)row * 8192 + col] = f2bf(v); });
  }
}

// out-proj GEMM + residual (h_bf) epilogue -> o2r bf16 [8192][512]; 512 blocks (2/CU)
__global__ __launch_bounds__(256) void gemm_out_kernel(
    const bf16_t* __restrict__ attn, const bf16_t* __restrict__ wfcT,
    const bf16_t* __restrict__ h_bf, bf16_t* __restrict__ o2r) {
  __shared__ __align__(16) bf16_t As[64 * 64];
  __shared__ __align__(16) bf16_t Bs[128 * 64];
  int bx = blockIdx.x;
  int m0 = (bx >> 2) * 64, n0 = (bx & 3) * 128;
  gemm_body_64x128(attn, wfcT, m0, n0, As, Bs, [&](int row, int col, float v) {
    size_t o = (size_t)row * 512 + col;
    o2r[o] = f2bf(v + bf2f(h_bf[o]));
  });
}

// ---------------- flash-style causal attention (S^T formulation) ----------------
// R6-proven body (46.8us; best of all schedule variants: pipeline/split-K/128q
// all neutral-to-worse). This round's single delta: T5 s_setprio(1) around the
// MFMA clusters — blocks sit at independent phases (5/CU, different qt), the
// regime where setprio paid on attn (m191); it only nulls on lockstep GEMMs.
__global__ __launch_bounds__(256) void attn_kernel(const bf16_t* __restrict__ qk,
                                                   const bf16_t* __restrict__ vT,
                                                   bf16_t* __restrict__ out) {
  __shared__ __align__(16) bf16_t Ks[2][64 * 64];
  __shared__ __align__(16) bf16_t Vs[2][64 * 64];
  const int bx = blockIdx.x;
  const int qt = 31 - (bx >> 5);      // long blocks first
  const int bh = bx & 31;
  const int b = bh >> 3, h = bh & 7;
  const int tid = threadIdx.x;
  const int w = tid >> 6, lane = tid & 63;
  const int ln = lane & 15, quad = lane >> 4;
  const int sw = ln & 7;

  short8 qf0, qf1;
  {
    size_t qrow = ((size_t)b * T_ + qt * 64 + w * 16 + ln) * 1024 + h * 64;
    qf0 = *(const short8*)(qk + qrow + quad * 8);
    qf1 = *(const short8*)(qk + qrow + 32 + quad * 8);
  }
  float4v z = {0.f, 0.f, 0.f, 0.f};
  float4v oacc[4];
#pragma unroll
  for (int i = 0; i < 4; ++i) oacc[i] = z;
  float m_s = -1e30f, l_s = 0.f;

  const bf16_t* kbase = qk + (size_t)b * T_ * 1024 + 512 + h * 64;
  const bf16_t* vbase = vT + (size_t)(h * 64) * 8192 + (size_t)b * T_;

  // hoisted per-lane staging addresses; advanced by constant strides per tile
  const int cb0 = w * 128, cb1 = w * 128 + 64;
  const int ch0 = cb0 + lane, ch1 = cb1 + lane;
  const int r0 = ch0 >> 3, r1 = ch1 >> 3;
  const int lb0 = (ch0 & 7) ^ (r0 & 7), lb1 = (ch1 & 7) ^ (r1 & 7);
  const bf16_t* kg0 = kbase + (size_t)r0 * 1024 + lb0 * 8;
  const bf16_t* kg1 = kbase + (size_t)r1 * 1024 + lb1 * 8;
  const bf16_t* vg0 = vbase + (size_t)r0 * 8192 + lb0 * 8;
  const bf16_t* vg1 = vbase + (size_t)r1 * 8192 + lb1 * 8;

  auto stage2 = [&](int buf) {
    gld16(kg0, Ks[buf] + cb0 * 8);
    gld16(kg1, Ks[buf] + cb1 * 8);
    gld16(vg0, Vs[buf] + cb0 * 8);
    gld16(vg1, Vs[buf] + cb1 * 8);
    kg0 += 64 * 1024; kg1 += 64 * 1024;   // next K tile (64 rows)
    vg0 += 64;        vg1 += 64;          // next V^T tile (64 cols)
  };

  auto compute = [&](const bf16_t* Kc, const bf16_t* Vc, bool mask) {
    float sv[4][4];
    __builtin_amdgcn_s_setprio(1);
#pragma unroll
    for (int mt = 0; mt < 4; ++mt) {
      float4v st = z;
      int row = mt * 16 + ln;
      short8 a0 = *(const short8*)(Kc + row * 64 + ((0 + quad) ^ sw) * 8);
      short8 a1 = *(const short8*)(Kc + row * 64 + ((4 + quad) ^ sw) * 8);
      st = __builtin_amdgcn_mfma_f32_16x16x32_bf16(a0, qf0, st, 0, 0, 0);
      st = __builtin_amdgcn_mfma_f32_16x16x32_bf16(a1, qf1, st, 0, 0, 0);
#pragma unroll
      for (int r = 0; r < 4; ++r) {
        float v = st[r];
        if (mask) {
          int kloc = mt * 16 + quad * 4 + r;
          if (kloc > w * 16 + ln) v = -1e30f;
        }
        sv[mt][r] = v;
      }
    }
    __builtin_amdgcn_s_setprio(0);
    float mx = sv[0][0];
#pragma unroll
    for (int mt = 0; mt < 4; ++mt)
#pragma unroll
      for (int r = 0; r < 4; ++r) mx = fmaxf(mx, sv[mt][r]);
    mx = fmaxf(mx, __shfl_xor(mx, 16, 64));
    mx = fmaxf(mx, __shfl_xor(mx, 32, 64));
    // defer-max: only rescale O when the per-row max actually grew beyond THR=8 (2^8 headroom)
    if (!__all(mx <= m_s + 8.0f)) {
      float mn = fmaxf(m_s, mx);
      float alpha = fast_exp2(m_s - mn);
      m_s = mn;
      l_s *= alpha;
#pragma unroll
      for (int dt = 0; dt < 4; ++dt)
#pragma unroll
        for (int r = 0; r < 4; ++r) oacc[dt][r] *= alpha;
    }
    float rs = 0.f;
#pragma unroll
    for (int mt = 0; mt < 4; ++mt)
#pragma unroll
      for (int r = 0; r < 4; ++r) {
        float p = fast_exp2(sv[mt][r] - m_s);
        sv[mt][r] = p;
        rs += p;
      }
    rs += __shfl_xor(rs, 16, 64);
    rs += __shfl_xor(rs, 32, 64);
    l_s += rs;
    // pack own 4 exp values per k-subtile -> bf16 B-frag in-register (v_cvt_pk RNE)
    short4v pf[4];
#pragma unroll
    for (int mt = 0; mt < 4; ++mt) {
      uint2 pp;
      pp.x = cvt_pk_bf16(sv[mt][0], sv[mt][1]);
      pp.y = cvt_pk_bf16(sv[mt][2], sv[mt][3]);
      pf[mt] = __builtin_bit_cast(short4v, pp);
    }
    // O^T += V^T P : A = V^T frags (m=d in lanes, k=quad*4+j), B = pf
    __builtin_amdgcn_s_setprio(1);
#pragma unroll
    for (int dt = 0; dt < 4; ++dt) {
      int row = dt * 16 + ln;
#pragma unroll
      for (int mt = 0; mt < 4; ++mt) {
        short4v av = *(const short4v*)(Vc + row * 64 + ((2 * mt + (quad >> 1)) ^ sw) * 8 + (quad & 1) * 4);
        oacc[dt] = __builtin_amdgcn_mfma_f32_16x16x16bf16_1k(av, pf[mt], oacc[dt], 0, 0, 0);
      }
    }
    __builtin_amdgcn_s_setprio(0);
  };

  stage2(0);
  __syncthreads();
  for (int kt = 0; kt < qt; ++kt) {
    int cur = kt & 1;
    stage2(cur ^ 1);
    compute(Ks[cur], Vs[cur], false);
    __syncthreads();
  }
  compute(Ks[qt & 1], Vs[qt & 1], true);

  float inv = 1.0f / l_s;
  size_t obase = ((size_t)b * T_ + qt * 64 + w * 16 + ln) * 512 + h * 64;
#pragma unroll
  for (int dt = 0; dt < 4; ++dt) {
    short4v o4;
#pragma unroll
    for (int r = 0; r < 4; ++r) o4[r] = (short)f2bf(oacc[dt][r] * inv);
    *(short4v*)(out + obase + dt * 16 + quad * 4) = o4;
  }
}

// ---------------- final LN + residual ----------------
__global__ __launch_bounds__(256) void ln2_kernel(
    const bf16_t* __restrict__ o2r, const float* __restrict__ x,
    const float* __restrict__ g, const float* __restrict__ bb,
    float* __restrict__ out) {
  int wave = threadIdx.x >> 6, lane = threadIdx.x & 63;
  int row = blockIdx.x * 4 + wave;
  size_t ro = (size_t)row * D_;
  int c0 = lane * 8;
  short8 ov = *(const short8*)(o2r + ro + c0);
  float t[8];
#pragma unroll
  for (int j = 0; j < 8; ++j) t[j] = bf2f((bf16_t)ov[j]);
  float s = 0.f;
#pragma unroll
  for (int j = 0; j < 8; ++j) s += t[j];
  s = waveReduceSum(s);
  float mu = s * (1.f / 512.f);
  float q = 0.f;
#pragma unroll
  for (int j = 0; j < 8; ++j) { float d = t[j] - mu; q += d * d; }
  q = waveReduceSum(q);
  float rstd = rsqrtf(q * (1.f / 512.f) + 1e-6f);
  float4 x0 = *(const float4*)(x + ro + c0);
  float4 x1 = *(const float4*)(x + ro + c0 + 4);
  float xr[8] = {x0.x, x0.y, x0.z, x0.w, x1.x, x1.y, x1.z, x1.w};
  float o[8];
#pragma unroll
  for (int j = 0; j < 8; ++j) {
    int col = c0 + j;
    o[j] = (t[j] - mu) * rstd * g[col] + bb[col] + xr[j];
  }
  float4 w0 = {o[0], o[1], o[2], o[3]};
  float4 w1 = {o[4], o[5], o[6], o[7]};
  *(float4*)(out + ro + c0) = w0;
  *(float4*)(out + ro + c0 + 4) = w1;
}

// ---------------- launch ----------------
extern "C" void kernel_launch(void* const* d_in, const int* in_sizes, int n_in,
                              void* d_out, int out_size, void* d_ws, size_t ws_size,
                              hipStream_t stream) {
  const float* x   = (const float*)d_in[0];
  const float* g1  = (const float*)d_in[1];
  const float* b1  = (const float*)d_in[2];
  const float* wq  = (const float*)d_in[3];
  const float* wk  = (const float*)d_in[4];
  const float* wv  = (const float*)d_in[5];
  const float* wfc = (const float*)d_in[6];
  const float* g2  = (const float*)d_in[7];
  const float* b2  = (const float*)d_in[8];
  float* out = (float*)d_out;

  char* ws = (char*)d_ws;
  const size_t O_HBF  = 0;          // 8192*512*2  =  8388608
  const size_t O_WQKV = 8388608;    // 1536*512*2  =  1572864
  const size_t O_WFC  = 9961472;    //  512*512*2  =   524288
  const size_t O_QK   = 10485760;   // 8192*1024*2 = 16777216
  const size_t O_VT   = 27262976;   //  512*8192*2 =  8388608
  const size_t O_ATTN = 35651584;   // 8192*512*2  =  8388608
  const size_t O_O2R  = 44040192;   // 8192*512*2  =  8388608
  const size_t WS_NEED = 52428800;
  if (ws_size < WS_NEED) return;

  bf16_t* h_bf  = (bf16_t*)(ws + O_HBF);
  bf16_t* wqkvT = (bf16_t*)(ws + O_WQKV);
  bf16_t* wfcT  = (bf16_t*)(ws + O_WFC);
  bf16_t* qk    = (bf16_t*)(ws + O_QK);
  bf16_t* vT    = (bf16_t*)(ws + O_VT);
  bf16_t* attn  = (bf16_t*)(ws + O_ATTN);
  bf16_t* o2r   = (bf16_t*)(ws + O_O2R);

  pre_kernel<<<dim3(2304), dim3(256), 0, stream>>>(x, g1, b1, wq, wk, wv, wfc,
                                                   h_bf, wqkvT, wfcT);
  gemm_qkvt_kernel<<<dim3(768), dim3(256), 0, stream>>>(h_bf, wqkvT, qk, vT);
  attn_kernel<<<dim3(1024), dim3(256), 0, stream>>>(qk, vT, attn);
  gemm_out_kernel<<<dim3(512), dim3(256), 0, stream>>>(attn, wfcT, h_bf, o2r);
  ln2_kernel<<<dim3(2048), dim3(256), 0, stream>>>(o2r, x, g2, b2, out);
}

// Round 10
// 161.967 us; speedup vs baseline: 1.1525x; 1.0198x over previous
//
#include <hip/hip_runtime.h>
#include <hip/hip_bf16.h>

#define B_ 4
#define T_ 2048
#define D_ 512

typedef __attribute__((ext_vector_type(8))) short short8;
typedef __attribute__((ext_vector_type(4))) short short4v;
typedef __attribute__((ext_vector_type(4))) float float4v;
typedef unsigned short bf16_t;

__device__ __forceinline__ bf16_t f2bf(float f) {
  unsigned int u = __builtin_bit_cast(unsigned int, f);
  unsigned int r = (u + 0x7fffu + ((u >> 16) & 1u)) >> 16;
  return (bf16_t)r;
}
__device__ __forceinline__ float bf2f(bf16_t b) {
  unsigned int u = ((unsigned int)b) << 16;
  return __builtin_bit_cast(float, u);
}

// raw 2^x (v_exp_f32). Args always in-range here (or hugely negative -> 0).
__device__ __forceinline__ float fast_exp2(float x) {
#if __has_builtin(__builtin_amdgcn_exp2f)
  return __builtin_amdgcn_exp2f(x);
#else
  float r;
  asm("v_exp_f32 %0, %1" : "=v"(r) : "v"(x));
  return r;
#endif
}

// pack two f32 -> two bf16 (RNE) in one instruction: lo = src0, hi = src1
__device__ __forceinline__ unsigned cvt_pk_bf16(float lo, float hi) {
  unsigned r;
  asm("v_cvt_pk_bf16_f32 %0, %1, %2" : "=v"(r) : "v"(lo), "v"(hi));
  return r;
}

__device__ __forceinline__ float waveReduceSum(float v) {
#pragma unroll
  for (int m = 32; m >= 1; m >>= 1) v += __shfl_xor(v, m, 64);
  return v;
}

// async global->LDS 16B: LDS dest = wave-uniform base + lane*16
__device__ __forceinline__ void gld16(const bf16_t* g, bf16_t* l) {
  __builtin_amdgcn_global_load_lds(
      (const __attribute__((address_space(1))) void*)g,
      (__attribute__((address_space(3))) void*)l, 16, 0, 0);
}

// ---------------- fused: weight convert/transpose + LN1+PE ----------------
// Blocks [0,2048): LN1+PE rows. Blocks [2048,2304): LDS-tiled 64x64 weight
// transpose (coalesced f32 reads). wq scaled by log2(e), wk by 0.125.
__global__ __launch_bounds__(256) void pre_kernel(
    const float* __restrict__ x, const float* __restrict__ g,
    const float* __restrict__ bb,
    const float* __restrict__ wq, const float* __restrict__ wk,
    const float* __restrict__ wv, const float* __restrict__ wfc,
    bf16_t* __restrict__ h_bf16,
    bf16_t* __restrict__ wqkvT, bf16_t* __restrict__ wfcT) {
  if (blockIdx.x >= 2048) {
    __shared__ float tl[64][65];
    int bid = blockIdx.x - 2048;
    const float* src;
    float scl;
    int n0, k0;
    bf16_t* dst;
    if (bid < 192) {                        // wq|wk|wv -> wqkvT[n][k], n in [0,1536)
      n0 = (bid >> 3) * 64;
      k0 = (bid & 7) * 64;
      int m = n0 >> 9;
      src = (m == 0) ? wq : ((m == 1) ? wk : wv);
      scl = (m == 0) ? 1.4426950408889634f : ((m == 1) ? 0.125f : 1.0f);
      dst = wqkvT;
    } else {                                // wfc -> wfcT[n][k]
      int local = bid - 192;
      n0 = (local >> 3) * 64;
      k0 = (local & 7) * 64;
      src = wfc;
      scl = 1.0f;
      dst = wfcT;
    }
    int c0 = n0 & 511;
    int jl = threadIdx.x & 63, bi = threadIdx.x >> 6;
#pragma unroll
    for (int it = 0; it < 16; ++it) {
      int i = it * 4 + bi;                  // k-offset; reads are 256B-coalesced per wave
      tl[jl][i] = src[(size_t)(k0 + i) * 512 + c0 + jl] * scl;
    }
    __syncthreads();
    int i2 = (threadIdx.x & 31) * 2, jb = threadIdx.x >> 5;
#pragma unroll
    for (int it = 0; it < 8; ++it) {
      int j = it * 8 + jb;                  // n-offset
      unsigned pk = cvt_pk_bf16(tl[j][i2], tl[j][i2 + 1]);
      *(unsigned*)(dst + (size_t)(n0 + j) * 512 + k0 + i2) = pk;
    }
    return;
  }
  int wave = threadIdx.x >> 6, lane = threadIdx.x & 63;
  int row = blockIdx.x * 4 + wave;
  int pos = row & (T_ - 1);
  const float* xr = x + (size_t)row * D_;
  int c0 = lane * 8;
  float v[8];
  float4 a = *(const float4*)(xr + c0);
  float4 b4 = *(const float4*)(xr + c0 + 4);
  v[0]=a.x; v[1]=a.y; v[2]=a.z; v[3]=a.w;
  v[4]=b4.x; v[5]=b4.y; v[6]=b4.z; v[7]=b4.w;
  float s = 0.f;
#pragma unroll
  for (int j = 0; j < 8; ++j) s += v[j];
  s = waveReduceSum(s);
  float mu = s * (1.f / 512.f);
  float q = 0.f;
#pragma unroll
  for (int j = 0; j < 8; ++j) { float d = v[j] - mu; q += d * d; }
  q = waveReduceSum(q);
  float rstd = rsqrtf(q * (1.f / 512.f) + 1e-5f);
  bf16_t* hb = h_bf16 + (size_t)row * D_;
  float fpos = (float)pos;
#pragma unroll
  for (int jp = 0; jp < 4; ++jp) {
    int col = c0 + jp * 2;
    float dt = fast_exp2((float)col * (-13.287712379549449f / 512.0f));
    float ang = fpos * dt;
    float hn0 = (v[2 * jp] - mu) * rstd * g[col] + bb[col] + __sinf(ang);
    float hn1 = (v[2 * jp + 1] - mu) * rstd * g[col + 1] + bb[col + 1] + __cosf(ang);
    hb[col] = f2bf(hn0);
    hb[col + 1] = f2bf(hn1);
  }
}

// ---------------- 128x128 GEMM, single-buffer m97 structure (32 KB LDS) ----------------
template <typename EPI>
__device__ __forceinline__ void gemm_body(const bf16_t* __restrict__ A,
                                          const bf16_t* __restrict__ Bt,
                                          int m0, int n0, bf16_t* As, bf16_t* Bs,
                                          EPI epi) {
  const int tid = threadIdx.x;
  const int w = tid >> 6, lane = tid & 63;
  const int ln = lane & 15, quad = lane >> 4;
  const int wy = w >> 1, wx = w & 1;
  const int sw = ln & 7;

  float4v acc[4][4];
  float4v z = {0.f, 0.f, 0.f, 0.f};
#pragma unroll
  for (int i = 0; i < 4; ++i)
#pragma unroll
    for (int j = 0; j < 4; ++j) acc[i][j] = z;

  for (int k0 = 0; k0 < 512; k0 += 64) {
#pragma unroll
    for (int i = 0; i < 4; ++i) {
      int cbase = w * 256 + i * 64;
      int chunk = cbase + lane;
      int row = chunk >> 3;
      int lb = (chunk & 7) ^ (row & 7);
      gld16(A + (size_t)(m0 + row) * 512 + k0 + lb * 8, As + cbase * 8);
      gld16(Bt + (size_t)(n0 + row) * 512 + k0 + lb * 8, Bs + cbase * 8);
    }
    __syncthreads();
#pragma unroll
    for (int c = 0; c < 2; ++c) {
      short8 af[4], bf[4];
#pragma unroll
      for (int mt = 0; mt < 4; ++mt)
        af[mt] = *(const short8*)(As + (wy * 64 + mt * 16 + ln) * 64 + (((c * 4 + quad) ^ sw)) * 8);
#pragma unroll
      for (int nt = 0; nt < 4; ++nt)
        bf[nt] = *(const short8*)(Bs + (wx * 64 + nt * 16 + ln) * 64 + (((c * 4 + quad) ^ sw)) * 8);
#pragma unroll
      for (int mt = 0; mt < 4; ++mt)
#pragma unroll
        for (int nt = 0; nt < 4; ++nt)
          acc[mt][nt] = __builtin_amdgcn_mfma_f32_16x16x32_bf16(af[mt], bf[nt], acc[mt][nt], 0, 0, 0);
    }
    __syncthreads();
  }
#pragma unroll
  for (int mt = 0; mt < 4; ++mt)
#pragma unroll
    for (int r = 0; r < 4; ++r) {
      int row = m0 + wy * 64 + mt * 16 + quad * 4 + r;
#pragma unroll
      for (int nt = 0; nt < 4; ++nt) {
        int col = n0 + wx * 64 + nt * 16 + ln;
        epi(row, col, acc[mt][nt][r]);
      }
    }
}

// ---------------- 64x128 GEMM body (24 KB LDS) — for the small out-proj ----------------
template <typename EPI>
__device__ __forceinline__ void gemm_body_64x128(const bf16_t* __restrict__ A,
                                                 const bf16_t* __restrict__ Bt,
                                                 int m0, int n0, bf16_t* As, bf16_t* Bs,
                                                 EPI epi) {
  const int tid = threadIdx.x;
  const int w = tid >> 6, lane = tid & 63;
  const int ln = lane & 15, quad = lane >> 4;
  const int wy = w >> 1, wx = w & 1;
  const int sw = ln & 7;

  float4v acc[2][4];
  float4v z = {0.f, 0.f, 0.f, 0.f};
#pragma unroll
  for (int i = 0; i < 2; ++i)
#pragma unroll
    for (int j = 0; j < 4; ++j) acc[i][j] = z;

  for (int k0 = 0; k0 < 512; k0 += 64) {
#pragma unroll
    for (int i = 0; i < 2; ++i) {           // A: 64 rows -> 512 chunks
      int cbase = i * 256 + w * 64;
      int chunk = cbase + lane;
      int row = chunk >> 3;
      int lb = (chunk & 7) ^ (row & 7);
      gld16(A + (size_t)(m0 + row) * 512 + k0 + lb * 8, As + cbase * 8);
    }
#pragma unroll
    for (int i = 0; i < 4; ++i) {           // B: 128 rows -> 1024 chunks
      int cbase = i * 256 + w * 64;
      int chunk = cbase + lane;
      int row = chunk >> 3;
      int lb = (chunk & 7) ^ (row & 7);
      gld16(Bt + (size_t)(n0 + row) * 512 + k0 + lb * 8, Bs + cbase * 8);
    }
    __syncthreads();
#pragma unroll
    for (int c = 0; c < 2; ++c) {
      short8 af[2], bf[4];
#pragma unroll
      for (int mt = 0; mt < 2; ++mt)
        af[mt] = *(const short8*)(As + (wy * 32 + mt * 16 + ln) * 64 + (((c * 4 + quad) ^ sw)) * 8);
#pragma unroll
      for (int nt = 0; nt < 4; ++nt)
        bf[nt] = *(const short8*)(Bs + (wx * 64 + nt * 16 + ln) * 64 + (((c * 4 + quad) ^ sw)) * 8);
#pragma unroll
      for (int mt = 0; mt < 2; ++mt)
#pragma unroll
        for (int nt = 0; nt < 4; ++nt)
          acc[mt][nt] = __builtin_amdgcn_mfma_f32_16x16x32_bf16(af[mt], bf[nt], acc[mt][nt], 0, 0, 0);
    }
    __syncthreads();
  }
#pragma unroll
  for (int mt = 0; mt < 2; ++mt)
#pragma unroll
    for (int r = 0; r < 4; ++r) {
      int row = m0 + wy * 32 + mt * 16 + quad * 4 + r;
#pragma unroll
      for (int nt = 0; nt < 4; ++nt) {
        int col = n0 + wx * 64 + nt * 16 + ln;
        epi(row, col, acc[mt][nt][r]);
      }
    }
}

// blocks [0,512): QK proj -> qk[8192][1024]; [512,768): V^T -> vT[512][8192]
__global__ __launch_bounds__(256) void gemm_qkvt_kernel(
    const bf16_t* __restrict__ h_bf, const bf16_t* __restrict__ wqkvT,
    bf16_t* __restrict__ qk, bf16_t* __restrict__ vT) {
  __shared__ __align__(16) bf16_t As[128 * 64];
  __shared__ __align__(16) bf16_t Bs[128 * 64];
  int bx = blockIdx.x;
  if (bx < 512) {
    int m0 = (bx >> 3) * 128, n0 = (bx & 7) * 128;
    gemm_body(h_bf, wqkvT, m0, n0, As, Bs,
              [&](int row, int col, float v) { qk[(size_t)row * 1024 + col] = f2bf(v); });
  } else {
    int local = bx - 512;
    int m0 = (local >> 6) * 128, n0 = (local & 63) * 128;
    gemm_body(wqkvT + 1024 * 512, h_bf, m0, n0, As, Bs,
              [&](int row, int col, float v) { vT[(size_t)row * 8192 + col] = f2bf(v); });
  }
}

// out-proj GEMM + residual (h_bf) epilogue -> o2r bf16 [8192][512]; 512 blocks (2/CU)
__global__ __launch_bounds__(256) void gemm_out_kernel(
    const bf16_t* __restrict__ attn, const bf16_t* __restrict__ wfcT,
    const bf16_t* __restrict__ h_bf, bf16_t* __restrict__ o2r) {
  __shared__ __align__(16) bf16_t As[64 * 64];
  __shared__ __align__(16) bf16_t Bs[128 * 64];
  int bx = blockIdx.x;
  int m0 = (bx >> 2) * 64, n0 = (bx & 3) * 128;
  gemm_body_64x128(attn, wfcT, m0, n0, As, Bs, [&](int row, int col, float v) {
    size_t o = (size_t)row * 512 + col;
    o2r[o] = f2bf(v + bf2f(h_bf[o]));
  });
}

// ---------------- flash-style causal attention (S^T formulation) ----------------
// R6-proven body (46.8us; schedule variants + setprio all neutral-to-worse).
// This round: (1) setprio reverted (R9: -3us); (2) l-sum DEFERRED — per-lane
// partial l_p (alpha-rescaled; valid since m_s/alpha are quad-uniform after the
// max reduce), cross-quad reduced ONCE at the end. Cuts 2 of 4 ds_bpermute
// shuffles per tile from the serial softmax chain (LDS-pipe ops). (3) tree max.
__global__ __launch_bounds__(256) void attn_kernel(const bf16_t* __restrict__ qk,
                                                   const bf16_t* __restrict__ vT,
                                                   bf16_t* __restrict__ out) {
  __shared__ __align__(16) bf16_t Ks[2][64 * 64];
  __shared__ __align__(16) bf16_t Vs[2][64 * 64];
  const int bx = blockIdx.x;
  const int qt = 31 - (bx >> 5);      // long blocks first
  const int bh = bx & 31;
  const int b = bh >> 3, h = bh & 7;
  const int tid = threadIdx.x;
  const int w = tid >> 6, lane = tid & 63;
  const int ln = lane & 15, quad = lane >> 4;
  const int sw = ln & 7;

  short8 qf0, qf1;
  {
    size_t qrow = ((size_t)b * T_ + qt * 64 + w * 16 + ln) * 1024 + h * 64;
    qf0 = *(const short8*)(qk + qrow + quad * 8);
    qf1 = *(const short8*)(qk + qrow + 32 + quad * 8);
  }
  float4v z = {0.f, 0.f, 0.f, 0.f};
  float4v oacc[4];
#pragma unroll
  for (int i = 0; i < 4; ++i) oacc[i] = z;
  float m_s = -1e30f, l_p = 0.f;      // l_p: per-lane partial (own 16 k-slots)

  const bf16_t* kbase = qk + (size_t)b * T_ * 1024 + 512 + h * 64;
  const bf16_t* vbase = vT + (size_t)(h * 64) * 8192 + (size_t)b * T_;

  // hoisted per-lane staging addresses; advanced by constant strides per tile
  const int cb0 = w * 128, cb1 = w * 128 + 64;
  const int ch0 = cb0 + lane, ch1 = cb1 + lane;
  const int r0 = ch0 >> 3, r1 = ch1 >> 3;
  const int lb0 = (ch0 & 7) ^ (r0 & 7), lb1 = (ch1 & 7) ^ (r1 & 7);
  const bf16_t* kg0 = kbase + (size_t)r0 * 1024 + lb0 * 8;
  const bf16_t* kg1 = kbase + (size_t)r1 * 1024 + lb1 * 8;
  const bf16_t* vg0 = vbase + (size_t)r0 * 8192 + lb0 * 8;
  const bf16_t* vg1 = vbase + (size_t)r1 * 8192 + lb1 * 8;

  auto stage2 = [&](int buf) {
    gld16(kg0, Ks[buf] + cb0 * 8);
    gld16(kg1, Ks[buf] + cb1 * 8);
    gld16(vg0, Vs[buf] + cb0 * 8);
    gld16(vg1, Vs[buf] + cb1 * 8);
    kg0 += 64 * 1024; kg1 += 64 * 1024;   // next K tile (64 rows)
    vg0 += 64;        vg1 += 64;          // next V^T tile (64 cols)
  };

  auto compute = [&](const bf16_t* Kc, const bf16_t* Vc, bool mask) {
    float sv[4][4];
#pragma unroll
    for (int mt = 0; mt < 4; ++mt) {
      float4v st = z;
      int row = mt * 16 + ln;
      short8 a0 = *(const short8*)(Kc + row * 64 + ((0 + quad) ^ sw) * 8);
      short8 a1 = *(const short8*)(Kc + row * 64 + ((4 + quad) ^ sw) * 8);
      st = __builtin_amdgcn_mfma_f32_16x16x32_bf16(a0, qf0, st, 0, 0, 0);
      st = __builtin_amdgcn_mfma_f32_16x16x32_bf16(a1, qf1, st, 0, 0, 0);
#pragma unroll
      for (int r = 0; r < 4; ++r) {
        float v = st[r];
        if (mask) {
          int kloc = mt * 16 + quad * 4 + r;
          if (kloc > w * 16 + ln) v = -1e30f;
        }
        sv[mt][r] = v;
      }
    }
    // tree max (short dependency chain), then cross-quad reduce (must stay per-tile)
    float mxa[4];
#pragma unroll
    for (int mt = 0; mt < 4; ++mt)
      mxa[mt] = fmaxf(fmaxf(sv[mt][0], sv[mt][1]), fmaxf(sv[mt][2], sv[mt][3]));
    float mx = fmaxf(fmaxf(mxa[0], mxa[1]), fmaxf(mxa[2], mxa[3]));
    mx = fmaxf(mx, __shfl_xor(mx, 16, 64));
    mx = fmaxf(mx, __shfl_xor(mx, 32, 64));
    // defer-max: only rescale O when the per-row max actually grew beyond THR=8 (2^8 headroom)
    if (!__all(mx <= m_s + 8.0f)) {
      float mn = fmaxf(m_s, mx);
      float alpha = fast_exp2(m_s - mn);   // quad-uniform: m_s and mx are
      m_s = mn;
      l_p *= alpha;                        // rescale per-lane partial identically
#pragma unroll
      for (int dt = 0; dt < 4; ++dt)
#pragma unroll
        for (int r = 0; r < 4; ++r) oacc[dt][r] *= alpha;
    }
    float rsa[4];
#pragma unroll
    for (int mt = 0; mt < 4; ++mt) {
#pragma unroll
      for (int r = 0; r < 4; ++r) sv[mt][r] = fast_exp2(sv[mt][r] - m_s);
      rsa[mt] = (sv[mt][0] + sv[mt][1]) + (sv[mt][2] + sv[mt][3]);
    }
    l_p += (rsa[0] + rsa[1]) + (rsa[2] + rsa[3]);   // NO per-tile shfls
    // pack own 4 exp values per k-subtile -> bf16 B-frag in-register (v_cvt_pk RNE)
    short4v pf[4];
#pragma unroll
    for (int mt = 0; mt < 4; ++mt) {
      uint2 pp;
      pp.x = cvt_pk_bf16(sv[mt][0], sv[mt][1]);
      pp.y = cvt_pk_bf16(sv[mt][2], sv[mt][3]);
      pf[mt] = __builtin_bit_cast(short4v, pp);
    }
    // O^T += V^T P : A = V^T frags (m=d in lanes, k=quad*4+j), B = pf
#pragma unroll
    for (int dt = 0; dt < 4; ++dt) {
      int row = dt * 16 + ln;
#pragma unroll
      for (int mt = 0; mt < 4; ++mt) {
        short4v av = *(const short4v*)(Vc + row * 64 + ((2 * mt + (quad >> 1)) ^ sw) * 8 + (quad & 1) * 4);
        oacc[dt] = __builtin_amdgcn_mfma_f32_16x16x16bf16_1k(av, pf[mt], oacc[dt], 0, 0, 0);
      }
    }
  };

  stage2(0);
  __syncthreads();
  for (int kt = 0; kt < qt; ++kt) {
    int cur = kt & 1;
    stage2(cur ^ 1);
    compute(Ks[cur], Vs[cur], false);
    __syncthreads();
  }
  compute(Ks[qt & 1], Vs[qt & 1], true);

  // deferred cross-quad l reduction (once per kernel, not per tile)
  float lsum = l_p;
  lsum += __shfl_xor(lsum, 16, 64);
  lsum += __shfl_xor(lsum, 32, 64);
  float inv = 1.0f / lsum;
  size_t obase = ((size_t)b * T_ + qt * 64 + w * 16 + ln) * 512 + h * 64;
#pragma unroll
  for (int dt = 0; dt < 4; ++dt) {
    short4v o4;
#pragma unroll
    for (int r = 0; r < 4; ++r) o4[r] = (short)f2bf(oacc[dt][r] * inv);
    *(short4v*)(out + obase + dt * 16 + quad * 4) = o4;
  }
}

// ---------------- final LN + residual ----------------
__global__ __launch_bounds__(256) void ln2_kernel(
    const bf16_t* __restrict__ o2r, const float* __restrict__ x,
    const float* __restrict__ g, const float* __restrict__ bb,
    float* __restrict__ out) {
  int wave = threadIdx.x >> 6, lane = threadIdx.x & 63;
  int row = blockIdx.x * 4 + wave;
  size_t ro = (size_t)row * D_;
  int c0 = lane * 8;
  short8 ov = *(const short8*)(o2r + ro + c0);
  float t[8];
#pragma unroll
  for (int j = 0; j < 8; ++j) t[j] = bf2f((bf16_t)ov[j]);
  float s = 0.f;
#pragma unroll
  for (int j = 0; j < 8; ++j) s += t[j];
  s = waveReduceSum(s);
  float mu = s * (1.f / 512.f);
  float q = 0.f;
#pragma unroll
  for (int j = 0; j < 8; ++j) { float d = t[j] - mu; q += d * d; }
  q = waveReduceSum(q);
  float rstd = rsqrtf(q * (1.f / 512.f) + 1e-6f);
  float4 x0 = *(const float4*)(x + ro + c0);
  float4 x1 = *(const float4*)(x + ro + c0 + 4);
  float xr[8] = {x0.x, x0.y, x0.z, x0.w, x1.x, x1.y, x1.z, x1.w};
  float o[8];
#pragma unroll
  for (int j = 0; j < 8; ++j) {
    int col = c0 + j;
    o[j] = (t[j] - mu) * rstd * g[col] + bb[col] + xr[j];
  }
  float4 w0 = {o[0], o[1], o[2], o[3]};
  float4 w1 = {o[4], o[5], o[6], o[7]};
  *(float4*)(out + ro + c0) = w0;
  *(float4*)(out + ro + c0 + 4) = w1;
}

// ---------------- launch ----------------
extern "C" void kernel_launch(void* const* d_in, const int* in_sizes, int n_in,
                              void* d_out, int out_size, void* d_ws, size_t ws_size,
                              hipStream_t stream) {
  const float* x   = (const float*)d_in[0];
  const float* g1  = (const float*)d_in[1];
  const float* b1  = (const float*)d_in[2];
  const float* wq  = (const float*)d_in[3];
  const float* wk  = (const float*)d_in[4];
  const float* wv  = (const float*)d_in[5];
  const float* wfc = (const float*)d_in[6];
  const float* g2  = (const float*)d_in[7];
  const float* b2  = (const float*)d_in[8];
  float* out = (float*)d_out;

  char* ws = (char*)d_ws;
  const size_t O_HBF  = 0;          // 8192*512*2  =  8388608
  const size_t O_WQKV = 8388608;    // 1536*512*2  =  1572864
  const size_t O_WFC  = 9961472;    //  512*512*2  =   524288
  const size_t O_QK   = 10485760;   // 8192*1024*2 = 16777216
  const size_t O_VT   = 27262976;   //  512*8192*2 =  8388608
  const size_t O_ATTN = 35651584;   // 8192*512*2  =  8388608
  const size_t O_O2R  = 44040192;   // 8192*512*2  =  8388608
  const size_t WS_NEED = 52428800;
  if (ws_size < WS_NEED) return;

  bf16_t* h_bf  = (bf16_t*)(ws + O_HBF);
  bf16_t* wqkvT = (bf16_t*)(ws + O_WQKV);
  bf16_t* wfcT  = (bf16_t*)(ws + O_WFC);
  bf16_t* qk    = (bf16_t*)(ws + O_QK);
  bf16_t* vT    = (bf16_t*)(ws + O_VT);
  bf16_t* attn  = (bf16_t*)(ws + O_ATTN);
  bf16_t* o2r   = (bf16_t*)(ws + O_O2R);

  pre_kernel<<<dim3(2304), dim3(256), 0, stream>>>(x, g1, b1, wq, wk, wv, wfc,
                                                   h_bf, wqkvT, wfcT);
  gemm_qkvt_kernel<<<dim3(768), dim3(256), 0, stream>>>(h_bf, wqkvT, qk, vT);
  attn_kernel<<<dim3(1024), dim3(256), 0, stream>>>(qk, vT, attn);
  gemm_out_kernel<<<dim3(512), dim3(256), 0, stream>>>(attn, wfcT, h_bf, o2r);
  ln2_kernel<<<dim3(2048), dim3(256), 0, stream>>>(o2r, x, g2, b2, out);
}

// Round 11
// 156.605 us; speedup vs baseline: 1.1919x; 1.0342x over previous
//
#include <hip/hip_runtime.h>
#include <hip/hip_bf16.h>

#define B_ 4
#define T_ 2048
#define D_ 512

typedef __attribute__((ext_vector_type(8))) short short8;
typedef __attribute__((ext_vector_type(4))) short short4v;
typedef __attribute__((ext_vector_type(4))) float float4v;
typedef unsigned short bf16_t;

__device__ __forceinline__ bf16_t f2bf(float f) {
  unsigned int u = __builtin_bit_cast(unsigned int, f);
  unsigned int r = (u + 0x7fffu + ((u >> 16) & 1u)) >> 16;
  return (bf16_t)r;
}
__device__ __forceinline__ float bf2f(bf16_t b) {
  unsigned int u = ((unsigned int)b) << 16;
  return __builtin_bit_cast(float, u);
}

// raw 2^x (v_exp_f32). Args always in-range here (or hugely negative -> 0).
__device__ __forceinline__ float fast_exp2(float x) {
#if __has_builtin(__builtin_amdgcn_exp2f)
  return __builtin_amdgcn_exp2f(x);
#else
  float r;
  asm("v_exp_f32 %0, %1" : "=v"(r) : "v"(x));
  return r;
#endif
}

// pack two f32 -> two bf16 (RNE) in one instruction: lo = src0, hi = src1
__device__ __forceinline__ unsigned cvt_pk_bf16(float lo, float hi) {
  unsigned r;
  asm("v_cvt_pk_bf16_f32 %0, %1, %2" : "=v"(r) : "v"(lo), "v"(hi));
  return r;
}

__device__ __forceinline__ float waveReduceSum(float v) {
#pragma unroll
  for (int m = 32; m >= 1; m >>= 1) v += __shfl_xor(v, m, 64);
  return v;
}

// async global->LDS 16B: LDS dest = wave-uniform base + lane*16
__device__ __forceinline__ void gld16(const bf16_t* g, bf16_t* l) {
  __builtin_amdgcn_global_load_lds(
      (const __attribute__((address_space(1))) void*)g,
      (__attribute__((address_space(3))) void*)l, 16, 0, 0);
}

// ---------------- fused: weight convert/transpose + LN1+PE ----------------
// Blocks [0,2048): LN1+PE rows. Blocks [2048,2304): LDS-tiled 64x64 weight
// transpose (coalesced f32 reads). wq scaled by log2(e), wk by 0.125.
__global__ __launch_bounds__(256) void pre_kernel(
    const float* __restrict__ x, const float* __restrict__ g,
    const float* __restrict__ bb,
    const float* __restrict__ wq, const float* __restrict__ wk,
    const float* __restrict__ wv, const float* __restrict__ wfc,
    bf16_t* __restrict__ h_bf16,
    bf16_t* __restrict__ wqkvT, bf16_t* __restrict__ wfcT) {
  if (blockIdx.x >= 2048) {
    __shared__ float tl[64][65];
    int bid = blockIdx.x - 2048;
    const float* src;
    float scl;
    int n0, k0;
    bf16_t* dst;
    if (bid < 192) {                        // wq|wk|wv -> wqkvT[n][k], n in [0,1536)
      n0 = (bid >> 3) * 64;
      k0 = (bid & 7) * 64;
      int m = n0 >> 9;
      src = (m == 0) ? wq : ((m == 1) ? wk : wv);
      scl = (m == 0) ? 1.4426950408889634f : ((m == 1) ? 0.125f : 1.0f);
      dst = wqkvT;
    } else {                                // wfc -> wfcT[n][k]
      int local = bid - 192;
      n0 = (local >> 3) * 64;
      k0 = (local & 7) * 64;
      src = wfc;
      scl = 1.0f;
      dst = wfcT;
    }
    int c0 = n0 & 511;
    int jl = threadIdx.x & 63, bi = threadIdx.x >> 6;
#pragma unroll
    for (int it = 0; it < 16; ++it) {
      int i = it * 4 + bi;                  // k-offset; reads are 256B-coalesced per wave
      tl[jl][i] = src[(size_t)(k0 + i) * 512 + c0 + jl] * scl;
    }
    __syncthreads();
    int i2 = (threadIdx.x & 31) * 2, jb = threadIdx.x >> 5;
#pragma unroll
    for (int it = 0; it < 8; ++it) {
      int j = it * 8 + jb;                  // n-offset
      unsigned pk = cvt_pk_bf16(tl[j][i2], tl[j][i2 + 1]);
      *(unsigned*)(dst + (size_t)(n0 + j) * 512 + k0 + i2) = pk;
    }
    return;
  }
  int wave = threadIdx.x >> 6, lane = threadIdx.x & 63;
  int row = blockIdx.x * 4 + wave;
  int pos = row & (T_ - 1);
  const float* xr = x + (size_t)row * D_;
  int c0 = lane * 8;
  float v[8];
  float4 a = *(const float4*)(xr + c0);
  float4 b4 = *(const float4*)(xr + c0 + 4);
  v[0]=a.x; v[1]=a.y; v[2]=a.z; v[3]=a.w;
  v[4]=b4.x; v[5]=b4.y; v[6]=b4.z; v[7]=b4.w;
  float s = 0.f;
#pragma unroll
  for (int j = 0; j < 8; ++j) s += v[j];
  s = waveReduceSum(s);
  float mu = s * (1.f / 512.f);
  float q = 0.f;
#pragma unroll
  for (int j = 0; j < 8; ++j) { float d = v[j] - mu; q += d * d; }
  q = waveReduceSum(q);
  float rstd = rsqrtf(q * (1.f / 512.f) + 1e-5f);
  bf16_t* hb = h_bf16 + (size_t)row * D_;
  float fpos = (float)pos;
#pragma unroll
  for (int jp = 0; jp < 4; ++jp) {
    int col = c0 + jp * 2;
    float dt = fast_exp2((float)col * (-13.287712379549449f / 512.0f));
    float ang = fpos * dt;
    float hn0 = (v[2 * jp] - mu) * rstd * g[col] + bb[col] + __sinf(ang);
    float hn1 = (v[2 * jp + 1] - mu) * rstd * g[col + 1] + bb[col + 1] + __cosf(ang);
    hb[col] = f2bf(hn0);
    hb[col + 1] = f2bf(hn1);
  }
}

// ---------------- 128x128 GEMM, single-buffer m97 structure (32 KB LDS) ----------------
template <typename EPI>
__device__ __forceinline__ void gemm_body(const bf16_t* __restrict__ A,
                                          const bf16_t* __restrict__ Bt,
                                          int m0, int n0, bf16_t* As, bf16_t* Bs,
                                          EPI epi) {
  const int tid = threadIdx.x;
  const int w = tid >> 6, lane = tid & 63;
  const int ln = lane & 15, quad = lane >> 4;
  const int wy = w >> 1, wx = w & 1;
  const int sw = ln & 7;

  float4v acc[4][4];
  float4v z = {0.f, 0.f, 0.f, 0.f};
#pragma unroll
  for (int i = 0; i < 4; ++i)
#pragma unroll
    for (int j = 0; j < 4; ++j) acc[i][j] = z;

  for (int k0 = 0; k0 < 512; k0 += 64) {
#pragma unroll
    for (int i = 0; i < 4; ++i) {
      int cbase = w * 256 + i * 64;
      int chunk = cbase + lane;
      int row = chunk >> 3;
      int lb = (chunk & 7) ^ (row & 7);
      gld16(A + (size_t)(m0 + row) * 512 + k0 + lb * 8, As + cbase * 8);
      gld16(Bt + (size_t)(n0 + row) * 512 + k0 + lb * 8, Bs + cbase * 8);
    }
    __syncthreads();
#pragma unroll
    for (int c = 0; c < 2; ++c) {
      short8 af[4], bf[4];
#pragma unroll
      for (int mt = 0; mt < 4; ++mt)
        af[mt] = *(const short8*)(As + (wy * 64 + mt * 16 + ln) * 64 + (((c * 4 + quad) ^ sw)) * 8);
#pragma unroll
      for (int nt = 0; nt < 4; ++nt)
        bf[nt] = *(const short8*)(Bs + (wx * 64 + nt * 16 + ln) * 64 + (((c * 4 + quad) ^ sw)) * 8);
#pragma unroll
      for (int mt = 0; mt < 4; ++mt)
#pragma unroll
        for (int nt = 0; nt < 4; ++nt)
          acc[mt][nt] = __builtin_amdgcn_mfma_f32_16x16x32_bf16(af[mt], bf[nt], acc[mt][nt], 0, 0, 0);
    }
    __syncthreads();
  }
#pragma unroll
  for (int mt = 0; mt < 4; ++mt)
#pragma unroll
    for (int r = 0; r < 4; ++r) {
      int row = m0 + wy * 64 + mt * 16 + quad * 4 + r;
#pragma unroll
      for (int nt = 0; nt < 4; ++nt) {
        int col = n0 + wx * 64 + nt * 16 + ln;
        epi(row, col, acc[mt][nt][r]);
      }
    }
}

// ---------------- 64x128 GEMM body (24 KB LDS) — for the small out-proj ----------------
template <typename EPI>
__device__ __forceinline__ void gemm_body_64x128(const bf16_t* __restrict__ A,
                                                 const bf16_t* __restrict__ Bt,
                                                 int m0, int n0, bf16_t* As, bf16_t* Bs,
                                                 EPI epi) {
  const int tid = threadIdx.x;
  const int w = tid >> 6, lane = tid & 63;
  const int ln = lane & 15, quad = lane >> 4;
  const int wy = w >> 1, wx = w & 1;
  const int sw = ln & 7;

  float4v acc[2][4];
  float4v z = {0.f, 0.f, 0.f, 0.f};
#pragma unroll
  for (int i = 0; i < 2; ++i)
#pragma unroll
    for (int j = 0; j < 4; ++j) acc[i][j] = z;

  for (int k0 = 0; k0 < 512; k0 += 64) {
#pragma unroll
    for (int i = 0; i < 2; ++i) {           // A: 64 rows -> 512 chunks
      int cbase = i * 256 + w * 64;
      int chunk = cbase + lane;
      int row = chunk >> 3;
      int lb = (chunk & 7) ^ (row & 7);
      gld16(A + (size_t)(m0 + row) * 512 + k0 + lb * 8, As + cbase * 8);
    }
#pragma unroll
    for (int i = 0; i < 4; ++i) {           // B: 128 rows -> 1024 chunks
      int cbase = i * 256 + w * 64;
      int chunk = cbase + lane;
      int row = chunk >> 3;
      int lb = (chunk & 7) ^ (row & 7);
      gld16(Bt + (size_t)(n0 + row) * 512 + k0 + lb * 8, Bs + cbase * 8);
    }
    __syncthreads();
#pragma unroll
    for (int c = 0; c < 2; ++c) {
      short8 af[2], bf[4];
#pragma unroll
      for (int mt = 0; mt < 2; ++mt)
        af[mt] = *(const short8*)(As + (wy * 32 + mt * 16 + ln) * 64 + (((c * 4 + quad) ^ sw)) * 8);
#pragma unroll
      for (int nt = 0; nt < 4; ++nt)
        bf[nt] = *(const short8*)(Bs + (wx * 64 + nt * 16 + ln) * 64 + (((c * 4 + quad) ^ sw)) * 8);
#pragma unroll
      for (int mt = 0; mt < 2; ++mt)
#pragma unroll
        for (int nt = 0; nt < 4; ++nt)
          acc[mt][nt] = __builtin_amdgcn_mfma_f32_16x16x32_bf16(af[mt], bf[nt], acc[mt][nt], 0, 0, 0);
    }
    __syncthreads();
  }
#pragma unroll
  for (int mt = 0; mt < 2; ++mt)
#pragma unroll
    for (int r = 0; r < 4; ++r) {
      int row = m0 + wy * 32 + mt * 16 + quad * 4 + r;
#pragma unroll
      for (int nt = 0; nt < 4; ++nt) {
        int col = n0 + wx * 64 + nt * 16 + ln;
        epi(row, col, acc[mt][nt][r]);
      }
    }
}

// blocks [0,512): QK proj -> qk[8192][1024]; [512,768): V^T -> vT[512][8192]
// T1 XCD swizzle: 8 consecutive logical blocks share an A-panel (QK region) /
// 64 share a wv-panel (V^T region); default dispatch round-robins them across
// 8 non-coherent L2s. Bijective chunk map (768%8==0): physical p -> orig
// (p%8)*96 + p/8 gives each XCD a contiguous logical range -> panel reuse
// becomes XCD-local L2 hits instead of repeated L3 fabric fetches.
__global__ __launch_bounds__(256) void gemm_qkvt_kernel(
    const bf16_t* __restrict__ h_bf, const bf16_t* __restrict__ wqkvT,
    bf16_t* __restrict__ qk, bf16_t* __restrict__ vT) {
  __shared__ __align__(16) bf16_t As[128 * 64];
  __shared__ __align__(16) bf16_t Bs[128 * 64];
  int p = blockIdx.x;
  int bx = (p & 7) * 96 + (p >> 3);   // 768 blocks -> 8 chunks of 96
  if (bx < 512) {
    int m0 = (bx >> 3) * 128, n0 = (bx & 7) * 128;
    gemm_body(h_bf, wqkvT, m0, n0, As, Bs,
              [&](int row, int col, float v) { qk[(size_t)row * 1024 + col] = f2bf(v); });
  } else {
    int local = bx - 512;
    int m0 = (local >> 6) * 128, n0 = (local & 63) * 128;
    gemm_body(wqkvT + 1024 * 512, h_bf, m0, n0, As, Bs,
              [&](int row, int col, float v) { vT[(size_t)row * 8192 + col] = f2bf(v); });
  }
}

// out-proj GEMM + residual (h_bf) epilogue -> o2r bf16 [8192][512]; 512 blocks (2/CU)
// T1 XCD swizzle: 4 consecutive logical blocks share each 64-row attn A-panel.
__global__ __launch_bounds__(256) void gemm_out_kernel(
    const bf16_t* __restrict__ attn, const bf16_t* __restrict__ wfcT,
    const bf16_t* __restrict__ h_bf, bf16_t* __restrict__ o2r) {
  __shared__ __align__(16) bf16_t As[64 * 64];
  __shared__ __align__(16) bf16_t Bs[128 * 64];
  int p = blockIdx.x;
  int bx = (p & 7) * 64 + (p >> 3);   // 512 blocks -> 8 chunks of 64
  int m0 = (bx >> 2) * 64, n0 = (bx & 3) * 128;
  gemm_body_64x128(attn, wfcT, m0, n0, As, Bs, [&](int row, int col, float v) {
    size_t o = (size_t)row * 512 + col;
    o2r[o] = f2bf(v + bf2f(h_bf[o]));
  });
}

// ---------------- flash-style causal attention (S^T formulation) ----------------
// R10 body — best measured config (46.5us): R6 structure + deferred l-sum +
// tree max. Six schedule/instruction variants all neutral-to-worse; attn is
// treated as saturated at this decomposition.
__global__ __launch_bounds__(256) void attn_kernel(const bf16_t* __restrict__ qk,
                                                   const bf16_t* __restrict__ vT,
                                                   bf16_t* __restrict__ out) {
  __shared__ __align__(16) bf16_t Ks[2][64 * 64];
  __shared__ __align__(16) bf16_t Vs[2][64 * 64];
  const int bx = blockIdx.x;
  const int qt = 31 - (bx >> 5);      // long blocks first
  const int bh = bx & 31;
  const int b = bh >> 3, h = bh & 7;
  const int tid = threadIdx.x;
  const int w = tid >> 6, lane = tid & 63;
  const int ln = lane & 15, quad = lane >> 4;
  const int sw = ln & 7;

  short8 qf0, qf1;
  {
    size_t qrow = ((size_t)b * T_ + qt * 64 + w * 16 + ln) * 1024 + h * 64;
    qf0 = *(const short8*)(qk + qrow + quad * 8);
    qf1 = *(const short8*)(qk + qrow + 32 + quad * 8);
  }
  float4v z = {0.f, 0.f, 0.f, 0.f};
  float4v oacc[4];
#pragma unroll
  for (int i = 0; i < 4; ++i) oacc[i] = z;
  float m_s = -1e30f, l_p = 0.f;      // l_p: per-lane partial (own 16 k-slots)

  const bf16_t* kbase = qk + (size_t)b * T_ * 1024 + 512 + h * 64;
  const bf16_t* vbase = vT + (size_t)(h * 64) * 8192 + (size_t)b * T_;

  // hoisted per-lane staging addresses; advanced by constant strides per tile
  const int cb0 = w * 128, cb1 = w * 128 + 64;
  const int ch0 = cb0 + lane, ch1 = cb1 + lane;
  const int r0 = ch0 >> 3, r1 = ch1 >> 3;
  const int lb0 = (ch0 & 7) ^ (r0 & 7), lb1 = (ch1 & 7) ^ (r1 & 7);
  const bf16_t* kg0 = kbase + (size_t)r0 * 1024 + lb0 * 8;
  const bf16_t* kg1 = kbase + (size_t)r1 * 1024 + lb1 * 8;
  const bf16_t* vg0 = vbase + (size_t)r0 * 8192 + lb0 * 8;
  const bf16_t* vg1 = vbase + (size_t)r1 * 8192 + lb1 * 8;

  auto stage2 = [&](int buf) {
    gld16(kg0, Ks[buf] + cb0 * 8);
    gld16(kg1, Ks[buf] + cb1 * 8);
    gld16(vg0, Vs[buf] + cb0 * 8);
    gld16(vg1, Vs[buf] + cb1 * 8);
    kg0 += 64 * 1024; kg1 += 64 * 1024;   // next K tile (64 rows)
    vg0 += 64;        vg1 += 64;          // next V^T tile (64 cols)
  };

  auto compute = [&](const bf16_t* Kc, const bf16_t* Vc, bool mask) {
    float sv[4][4];
#pragma unroll
    for (int mt = 0; mt < 4; ++mt) {
      float4v st = z;
      int row = mt * 16 + ln;
      short8 a0 = *(const short8*)(Kc + row * 64 + ((0 + quad) ^ sw) * 8);
      short8 a1 = *(const short8*)(Kc + row * 64 + ((4 + quad) ^ sw) * 8);
      st = __builtin_amdgcn_mfma_f32_16x16x32_bf16(a0, qf0, st, 0, 0, 0);
      st = __builtin_amdgcn_mfma_f32_16x16x32_bf16(a1, qf1, st, 0, 0, 0);
#pragma unroll
      for (int r = 0; r < 4; ++r) {
        float v = st[r];
        if (mask) {
          int kloc = mt * 16 + quad * 4 + r;
          if (kloc > w * 16 + ln) v = -1e30f;
        }
        sv[mt][r] = v;
      }
    }
    // tree max (short dependency chain), then cross-quad reduce (must stay per-tile)
    float mxa[4];
#pragma unroll
    for (int mt = 0; mt < 4; ++mt)
      mxa[mt] = fmaxf(fmaxf(sv[mt][0], sv[mt][1]), fmaxf(sv[mt][2], sv[mt][3]));
    float mx = fmaxf(fmaxf(mxa[0], mxa[1]), fmaxf(mxa[2], mxa[3]));
    mx = fmaxf(mx, __shfl_xor(mx, 16, 64));
    mx = fmaxf(mx, __shfl_xor(mx, 32, 64));
    // defer-max: only rescale O when the per-row max actually grew beyond THR=8 (2^8 headroom)
    if (!__all(mx <= m_s + 8.0f)) {
      float mn = fmaxf(m_s, mx);
      float alpha = fast_exp2(m_s - mn);   // quad-uniform: m_s and mx are
      m_s = mn;
      l_p *= alpha;                        // rescale per-lane partial identically
#pragma unroll
      for (int dt = 0; dt < 4; ++dt)
#pragma unroll
        for (int r = 0; r < 4; ++r) oacc[dt][r] *= alpha;
    }
    float rsa[4];
#pragma unroll
    for (int mt = 0; mt < 4; ++mt) {
#pragma unroll
      for (int r = 0; r < 4; ++r) sv[mt][r] = fast_exp2(sv[mt][r] - m_s);
      rsa[mt] = (sv[mt][0] + sv[mt][1]) + (sv[mt][2] + sv[mt][3]);
    }
    l_p += (rsa[0] + rsa[1]) + (rsa[2] + rsa[3]);   // NO per-tile shfls
    // pack own 4 exp values per k-subtile -> bf16 B-frag in-register (v_cvt_pk RNE)
    short4v pf[4];
#pragma unroll
    for (int mt = 0; mt < 4; ++mt) {
      uint2 pp;
      pp.x = cvt_pk_bf16(sv[mt][0], sv[mt][1]);
      pp.y = cvt_pk_bf16(sv[mt][2], sv[mt][3]);
      pf[mt] = __builtin_bit_cast(short4v, pp);
    }
    // O^T += V^T P : A = V^T frags (m=d in lanes, k=quad*4+j), B = pf
#pragma unroll
    for (int dt = 0; dt < 4; ++dt) {
      int row = dt * 16 + ln;
#pragma unroll
      for (int mt = 0; mt < 4; ++mt) {
        short4v av = *(const short4v*)(Vc + row * 64 + ((2 * mt + (quad >> 1)) ^ sw) * 8 + (quad & 1) * 4);
        oacc[dt] = __builtin_amdgcn_mfma_f32_16x16x16bf16_1k(av, pf[mt], oacc[dt], 0, 0, 0);
      }
    }
  };

  stage2(0);
  __syncthreads();
  for (int kt = 0; kt < qt; ++kt) {
    int cur = kt & 1;
    stage2(cur ^ 1);
    compute(Ks[cur], Vs[cur], false);
    __syncthreads();
  }
  compute(Ks[qt & 1], Vs[qt & 1], true);

  // deferred cross-quad l reduction (once per kernel, not per tile)
  float lsum = l_p;
  lsum += __shfl_xor(lsum, 16, 64);
  lsum += __shfl_xor(lsum, 32, 64);
  float inv = 1.0f / lsum;
  size_t obase = ((size_t)b * T_ + qt * 64 + w * 16 + ln) * 512 + h * 64;
#pragma unroll
  for (int dt = 0; dt < 4; ++dt) {
    short4v o4;
#pragma unroll
    for (int r = 0; r < 4; ++r) o4[r] = (short)f2bf(oacc[dt][r] * inv);
    *(short4v*)(out + obase + dt * 16 + quad * 4) = o4;
  }
}

// ---------------- final LN + residual ----------------
__global__ __launch_bounds__(256) void ln2_kernel(
    const bf16_t* __restrict__ o2r, const float* __restrict__ x,
    const float* __restrict__ g, const float* __restrict__ bb,
    float* __restrict__ out) {
  int wave = threadIdx.x >> 6, lane = threadIdx.x & 63;
  int row = blockIdx.x * 4 + wave;
  size_t ro = (size_t)row * D_;
  int c0 = lane * 8;
  short8 ov = *(const short8*)(o2r + ro + c0);
  float t[8];
#pragma unroll
  for (int j = 0; j < 8; ++j) t[j] = bf2f((bf16_t)ov[j]);
  float s = 0.f;
#pragma unroll
  for (int j = 0; j < 8; ++j) s += t[j];
  s = waveReduceSum(s);
  float mu = s * (1.f / 512.f);
  float q = 0.f;
#pragma unroll
  for (int j = 0; j < 8; ++j) { float d = t[j] - mu; q += d * d; }
  q = waveReduceSum(q);
  float rstd = rsqrtf(q * (1.f / 512.f) + 1e-6f);
  float4 x0 = *(const float4*)(x + ro + c0);
  float4 x1 = *(const float4*)(x + ro + c0 + 4);
  float xr[8] = {x0.x, x0.y, x0.z, x0.w, x1.x, x1.y, x1.z, x1.w};
  float o[8];
#pragma unroll
  for (int j = 0; j < 8; ++j) {
    int col = c0 + j;
    o[j] = (t[j] - mu) * rstd * g[col] + bb[col] + xr[j];
  }
  float4 w0 = {o[0], o[1], o[2], o[3]};
  float4 w1 = {o[4], o[5], o[6], o[7]};
  *(float4*)(out + ro + c0) = w0;
  *(float4*)(out + ro + c0 + 4) = w1;
}

// ---------------- launch ----------------
extern "C" void kernel_launch(void* const* d_in, const int* in_sizes, int n_in,
                              void* d_out, int out_size, void* d_ws, size_t ws_size,
                              hipStream_t stream) {
  const float* x   = (const float*)d_in[0];
  const float* g1  = (const float*)d_in[1];
  const float* b1  = (const float*)d_in[2];
  const float* wq  = (const float*)d_in[3];
  const float* wk  = (const float*)d_in[4];
  const float* wv  = (const float*)d_in[5];
  const float* wfc = (const float*)d_in[6];
  const float* g2  = (const float*)d_in[7];
  const float* b2  = (const float*)d_in[8];
  float* out = (float*)d_out;

  char* ws = (char*)d_ws;
  const size_t O_HBF  = 0;          // 8192*512*2  =  8388608
  const size_t O_WQKV = 8388608;    // 1536*512*2  =  1572864
  const size_t O_WFC  = 9961472;    //  512*512*2  =   524288
  const size_t O_QK   = 10485760;   // 8192*1024*2 = 16777216
  const size_t O_VT   = 27262976;   //  512*8192*2 =  8388608
  const size_t O_ATTN = 35651584;   // 8192*512*2  =  8388608
  const size_t O_O2R  = 44040192;   // 8192*512*2  =  8388608
  const size_t WS_NEED = 52428800;
  if (ws_size < WS_NEED) return;

  bf16_t* h_bf  = (bf16_t*)(ws + O_HBF);
  bf16_t* wqkvT = (bf16_t*)(ws + O_WQKV);
  bf16_t* wfcT  = (bf16_t*)(ws + O_WFC);
  bf16_t* qk    = (bf16_t*)(ws + O_QK);
  bf16_t* vT    = (bf16_t*)(ws + O_VT);
  bf16_t* attn  = (bf16_t*)(ws + O_ATTN);
  bf16_t* o2r   = (bf16_t*)(ws + O_O2R);

  pre_kernel<<<dim3(2304), dim3(256), 0, stream>>>(x, g1, b1, wq, wk, wv, wfc,
                                                   h_bf, wqkvT, wfcT);
  gemm_qkvt_kernel<<<dim3(768), dim3(256), 0, stream>>>(h_bf, wqkvT, qk, vT);
  attn_kernel<<<dim3(1024), dim3(256), 0, stream>>>(qk, vT, attn);
  gemm_out_kernel<<<dim3(512), dim3(256), 0, stream>>>(attn, wfcT, h_bf, o2r);
  ln2_kernel<<<dim3(2048), dim3(256), 0, stream>>>(o2r, x, g2, b2, out);
}